// Round 1
// baseline (930.950 us; speedup 1.0000x reference)
//
#include <hip/hip_runtime.h>
#include <math.h>

#define N_NODES 50000
#define F_IN    512
#define HID     128
#define OUT_C   40
#define E_EDGES 800000

// ---------------- degree / norm ----------------

__global__ void k_init_deg(float* __restrict__ deg) {
    int i = blockIdx.x * blockDim.x + threadIdx.x;
    if (i < N_NODES) deg[i] = 1.0f;   // self-loop weight 1
}

__global__ void k_deg(const int* __restrict__ col, const float* __restrict__ w,
                      float* __restrict__ deg) {
    int e = blockIdx.x * blockDim.x + threadIdx.x;
    if (e < E_EDGES) atomicAdd(&deg[col[e]], w[e]);
}

__global__ void k_dinv(float* __restrict__ deg) {
    int i = blockIdx.x * blockDim.x + threadIdx.x;
    if (i < N_NODES) {
        float d = deg[i];
        deg[i] = (d > 0.0f) ? rsqrtf(d) : 0.0f;
    }
}

__global__ void k_norm(const int* __restrict__ row, const int* __restrict__ col,
                       const float* __restrict__ w, const float* __restrict__ dinv,
                       float* __restrict__ norm) {
    int e = blockIdx.x * blockDim.x + threadIdx.x;
    if (e < E_EDGES) norm[e] = dinv[row[e]] * w[e] * dinv[col[e]];
}

// ---------------- GEMM1: H1[50000,128] = X[50000,512] @ W1[512,128] ----------------

__global__ __launch_bounds__(256) void k_gemm1(const float* __restrict__ X,
                                               const float* __restrict__ W,
                                               float* __restrict__ H) {
    __shared__ float Xs[32][68];    // [k][m], padded (68 % 4 == 0 for float4)
    __shared__ float Ws[32][128];   // [k][n]
    const int tid = threadIdx.x;
    const int tx = tid & 15;        // col group: cols tx*8 .. tx*8+7
    const int ty = tid >> 4;        // row group: rows ty*4 .. ty*4+3
    const int row0 = blockIdx.x * 64;

    float acc[4][8];
#pragma unroll
    for (int i = 0; i < 4; i++)
#pragma unroll
        for (int j = 0; j < 8; j++) acc[i][j] = 0.0f;

    for (int k0 = 0; k0 < F_IN; k0 += 32) {
        // stage X tile 64x32 (transposed into Xs[k][m])
#pragma unroll
        for (int i = 0; i < 8; i++) {
            int l = tid + i * 256;
            int r = l >> 5;
            int kk = l & 31;
            int grow = row0 + r;
            float v = (grow < N_NODES) ? X[(size_t)grow * F_IN + k0 + kk] : 0.0f;
            Xs[kk][r] = v;
        }
        // stage W tile 32x128
#pragma unroll
        for (int i = 0; i < 16; i++) {
            int l = tid + i * 256;
            int kk = l >> 7;
            int c = l & 127;
            Ws[kk][c] = W[(size_t)(k0 + kk) * HID + c];
        }
        __syncthreads();
#pragma unroll
        for (int kk = 0; kk < 32; ++kk) {
            float4 a  = *(const float4*)(&Xs[kk][ty * 4]);
            float4 b0 = *(const float4*)(&Ws[kk][tx * 8]);
            float4 b1 = *(const float4*)(&Ws[kk][tx * 8 + 4]);
            float av[4] = {a.x, a.y, a.z, a.w};
            float bv[8] = {b0.x, b0.y, b0.z, b0.w, b1.x, b1.y, b1.z, b1.w};
#pragma unroll
            for (int i = 0; i < 4; i++)
#pragma unroll
                for (int j = 0; j < 8; j++)
                    acc[i][j] = fmaf(av[i], bv[j], acc[i][j]);
        }
        __syncthreads();
    }

#pragma unroll
    for (int i = 0; i < 4; i++) {
        int r = row0 + ty * 4 + i;
        if (r < N_NODES) {
            float4 s0 = make_float4(acc[i][0], acc[i][1], acc[i][2], acc[i][3]);
            float4 s1 = make_float4(acc[i][4], acc[i][5], acc[i][6], acc[i][7]);
            *(float4*)(&H[(size_t)r * HID + tx * 8])     = s0;
            *(float4*)(&H[(size_t)r * HID + tx * 8 + 4]) = s1;
        }
    }
}

// ---------------- aggregation layer 1 ----------------

__global__ void k_selfinit1(const float* __restrict__ dinv, const float* __restrict__ H1,
                            float* __restrict__ A1) {
    int idx = blockIdx.x * blockDim.x + threadIdx.x;
    if (idx < N_NODES * HID) {
        int i = idx >> 7;
        float di = dinv[i];
        A1[idx] = di * di * H1[idx];
    }
}

__global__ void k_agg1(const int* __restrict__ row, const int* __restrict__ col,
                       const float* __restrict__ norm, const float* __restrict__ H1,
                       float* __restrict__ A1) {
    int t = blockIdx.x * blockDim.x + threadIdx.x;   // E*128 = 102.4M < 2^31
    if (t < E_EDGES * HID) {
        int e = t >> 7;
        int c = t & 127;
        atomicAdd(&A1[(size_t)col[e] * HID + c], H1[(size_t)row[e] * HID + c] * norm[e]);
    }
}

__global__ void k_relubias(float* __restrict__ A1, const float* __restrict__ b1) {
    int idx = blockIdx.x * blockDim.x + threadIdx.x;
    if (idx < N_NODES * HID) {
        int c = idx & 127;
        A1[idx] = fmaxf(A1[idx] + b1[c], 0.0f);
    }
}

// ---------------- GEMM2: H2[50000,40] = A1[50000,128] @ W2[128,40] ----------------

__global__ __launch_bounds__(256) void k_gemm2(const float* __restrict__ A1,
                                               const float* __restrict__ W2,
                                               float* __restrict__ H2) {
    __shared__ float Hs[64][129];
    __shared__ float Ws[128][40];
    const int tid = threadIdx.x;
    const int row0 = blockIdx.x * 64;

    for (int i = tid; i < HID * OUT_C; i += 256) Ws[i / OUT_C][i % OUT_C] = W2[i];
    for (int i = tid; i < 64 * HID; i += 256) {
        int r = i >> 7, k = i & 127;
        int grow = row0 + r;
        Hs[r][k] = (grow < N_NODES) ? A1[(size_t)grow * HID + k] : 0.0f;
    }
    __syncthreads();

    const int r  = tid >> 2;            // 0..63
    const int c0 = (tid & 3) * 10;      // 0,10,20,30
    float acc[10];
#pragma unroll
    for (int j = 0; j < 10; j++) acc[j] = 0.0f;

    for (int k = 0; k < HID; k++) {
        float h = Hs[r][k];
#pragma unroll
        for (int j = 0; j < 10; j++) acc[j] = fmaf(h, Ws[k][c0 + j], acc[j]);
    }

    int grow = row0 + r;
    if (grow < N_NODES) {
#pragma unroll
        for (int j = 0; j < 10; j++) H2[(size_t)grow * OUT_C + c0 + j] = acc[j];
    }
}

// ---------------- aggregation layer 2 + bias ----------------

__global__ void k_selfinit2(const float* __restrict__ dinv, const float* __restrict__ H2,
                            const float* __restrict__ b2, float* __restrict__ A2) {
    int idx = blockIdx.x * blockDim.x + threadIdx.x;
    if (idx < N_NODES * OUT_C) {
        int i = idx / OUT_C;
        int c = idx - i * OUT_C;
        float di = dinv[i];
        A2[idx] = di * di * H2[idx] + b2[c];
    }
}

__global__ void k_agg2(const int* __restrict__ row, const int* __restrict__ col,
                       const float* __restrict__ norm, const float* __restrict__ H2,
                       float* __restrict__ A2) {
    int t = blockIdx.x * blockDim.x + threadIdx.x;   // E*40 = 32M
    if (t < E_EDGES * OUT_C) {
        int e = t / OUT_C;
        int c = t - e * OUT_C;
        atomicAdd(&A2[(size_t)col[e] * OUT_C + c], H2[(size_t)row[e] * OUT_C + c] * norm[e]);
    }
}

// ---------------- log_softmax (one wave per row) ----------------

__global__ __launch_bounds__(256) void k_logsoftmax(const float* __restrict__ A2,
                                                    float* __restrict__ out) {
    const int lane = threadIdx.x & 63;
    const int wrow = threadIdx.x >> 6;
    const int rown = blockIdx.x * 4 + wrow;
    if (rown >= N_NODES) return;

    float v = (lane < OUT_C) ? A2[(size_t)rown * OUT_C + lane] : -INFINITY;
    float m = v;
#pragma unroll
    for (int off = 32; off > 0; off >>= 1) m = fmaxf(m, __shfl_xor(m, off));
    float ex = (lane < OUT_C) ? __expf(v - m) : 0.0f;
    float s = ex;
#pragma unroll
    for (int off = 32; off > 0; off >>= 1) s += __shfl_xor(s, off);
    if (lane < OUT_C) out[(size_t)rown * OUT_C + lane] = v - m - __logf(s);
}

// ---------------- launch ----------------

extern "C" void kernel_launch(void* const* d_in, const int* in_sizes, int n_in,
                              void* d_out, int out_size, void* d_ws, size_t ws_size,
                              hipStream_t stream) {
    const float* x  = (const float*)d_in[0];
    const int*   ei = (const int*)d_in[1];          // [2, E] int32
    const float* ew = (const float*)d_in[2];
    const float* W1 = (const float*)d_in[3];
    const float* b1 = (const float*)d_in[4];
    const float* W2 = (const float*)d_in[5];
    const float* b2 = (const float*)d_in[6];
    float* out = (float*)d_out;

    const int* row = ei;            // sources
    const int* col = ei + E_EDGES;  // targets

    float* ws   = (float*)d_ws;
    float* deg  = ws;                       // 50048 (dinv stored in place)
    float* norm = ws + 50048;               // 800000
    float* H1   = norm + E_EDGES;           // 6,400,000
    float* A1   = H1 + (size_t)N_NODES*HID; // 6,400,000
    float* H2   = H1;                       // reuse (H1 dead after agg1)
    float* A2   = A1;                       // reuse (A1 dead after gemm2)

    const int B = 256;

    k_init_deg<<<(N_NODES + B - 1) / B, B, 0, stream>>>(deg);
    k_deg<<<(E_EDGES + B - 1) / B, B, 0, stream>>>(col, ew, deg);
    k_dinv<<<(N_NODES + B - 1) / B, B, 0, stream>>>(deg);
    k_norm<<<(E_EDGES + B - 1) / B, B, 0, stream>>>(row, col, ew, deg, norm);

    k_gemm1<<<(N_NODES + 63) / 64, B, 0, stream>>>(x, W1, H1);

    k_selfinit1<<<(N_NODES * HID) / B, B, 0, stream>>>(deg, H1, A1);
    k_agg1<<<(E_EDGES * HID) / B, B, 0, stream>>>(row, col, norm, H1, A1);
    k_relubias<<<(N_NODES * HID) / B, B, 0, stream>>>(A1, b1);

    k_gemm2<<<(N_NODES + 63) / 64, B, 0, stream>>>(A1, W2, H2);

    k_selfinit2<<<(N_NODES * OUT_C + B - 1) / B, B, 0, stream>>>(deg, H2, b2, A2);
    k_agg2<<<(E_EDGES * OUT_C + B - 1) / B, B, 0, stream>>>(row, col, norm, H2, A2);

    k_logsoftmax<<<(N_NODES + 3) / 4, B, 0, stream>>>(A2, out);
}

// Round 2
// 729.498 us; speedup vs baseline: 1.2762x; 1.2762x over previous
//
#include <hip/hip_runtime.h>
#include <math.h>

#define N_NODES 50000
#define F_IN    512
#define HID     128
#define OUT_C   40
#define E_EDGES 800000
#define SCAN_BLOCKS 196   // ceil(50000/256)

// ---------------- degree + edge-count ----------------

__global__ void k_init(float* __restrict__ deg, int* __restrict__ cnt) {
    int i = blockIdx.x * blockDim.x + threadIdx.x;
    if (i < N_NODES) { deg[i] = 1.0f; cnt[i] = 0; }   // self-loop weight 1
}

__global__ void k_deg_cnt(const int* __restrict__ col, const float* __restrict__ w,
                          float* __restrict__ deg, int* __restrict__ cnt) {
    int e = blockIdx.x * blockDim.x + threadIdx.x;
    if (e < E_EDGES) {
        int c = col[e];
        atomicAdd(&deg[c], w[e]);
        atomicAdd(&cnt[c], 1);
    }
}

__global__ void k_dinv(float* __restrict__ deg) {
    int i = blockIdx.x * blockDim.x + threadIdx.x;
    if (i < N_NODES) {
        float d = deg[i];
        deg[i] = (d > 0.0f) ? rsqrtf(d) : 0.0f;
    }
}

// ---------------- exclusive scan of cnt -> rowptr (3-stage) ----------------

__global__ __launch_bounds__(256) void k_scan1(const int* __restrict__ cnt,
                                               int* __restrict__ excl,
                                               int* __restrict__ bsum) {
    __shared__ int s[256];
    int tid = threadIdx.x;
    int i = blockIdx.x * 256 + tid;
    int v = (i < N_NODES) ? cnt[i] : 0;
    s[tid] = v;
    __syncthreads();
#pragma unroll
    for (int off = 1; off < 256; off <<= 1) {
        int t = (tid >= off) ? s[tid - off] : 0;
        __syncthreads();
        s[tid] += t;
        __syncthreads();
    }
    if (i < N_NODES) excl[i] = s[tid] - v;
    if (tid == 255) bsum[blockIdx.x] = s[255];
}

__global__ __launch_bounds__(256) void k_scan2(int* __restrict__ bsum) {
    __shared__ int s[256];
    int tid = threadIdx.x;
    int v = (tid < SCAN_BLOCKS) ? bsum[tid] : 0;
    s[tid] = v;
    __syncthreads();
#pragma unroll
    for (int off = 1; off < 256; off <<= 1) {
        int t = (tid >= off) ? s[tid - off] : 0;
        __syncthreads();
        s[tid] += t;
        __syncthreads();
    }
    if (tid < SCAN_BLOCKS) bsum[tid] = s[tid] - v;   // exclusive
}

__global__ __launch_bounds__(256) void k_scan3(int* __restrict__ rowptr,
                                               const int* __restrict__ bsum,
                                               int* __restrict__ cursor) {
    int i = blockIdx.x * 256 + threadIdx.x;
    if (i < N_NODES) {
        int v = rowptr[i] + bsum[blockIdx.x];
        rowptr[i] = v;
        cursor[i] = v;
    }
    if (i == 0) rowptr[N_NODES] = E_EDGES;
}

// ---------------- scatter edges into CSR order (fold norm) ----------------

__global__ void k_scatter(const int* __restrict__ row, const int* __restrict__ col,
                          const float* __restrict__ w, const float* __restrict__ dinv,
                          int* __restrict__ cursor,
                          int* __restrict__ src_s, float* __restrict__ norm_s) {
    int e = blockIdx.x * blockDim.x + threadIdx.x;
    if (e < E_EDGES) {
        int r = row[e], c = col[e];
        float nm = dinv[r] * w[e] * dinv[c];
        int pos = atomicAdd(&cursor[c], 1);
        src_s[pos] = r;
        norm_s[pos] = nm;
    }
}

// ---------------- GEMM1: H1[50000,128] = X[50000,512] @ W1[512,128] ----------------

__global__ __launch_bounds__(256) void k_gemm1(const float* __restrict__ X,
                                               const float* __restrict__ W,
                                               float* __restrict__ H) {
    __shared__ float Xs[32][68];    // [k][m], padded
    __shared__ float Ws[32][128];   // [k][n]
    const int tid = threadIdx.x;
    const int tx = tid & 15;        // col group: cols tx*8 .. tx*8+7
    const int ty = tid >> 4;        // row group: rows ty*4 .. ty*4+3
    const int row0 = blockIdx.x * 64;

    float acc[4][8];
#pragma unroll
    for (int i = 0; i < 4; i++)
#pragma unroll
        for (int j = 0; j < 8; j++) acc[i][j] = 0.0f;

    for (int k0 = 0; k0 < F_IN; k0 += 32) {
#pragma unroll
        for (int i = 0; i < 8; i++) {
            int l = tid + i * 256;
            int r = l >> 5;
            int kk = l & 31;
            int grow = row0 + r;
            float v = (grow < N_NODES) ? X[(size_t)grow * F_IN + k0 + kk] : 0.0f;
            Xs[kk][r] = v;
        }
#pragma unroll
        for (int i = 0; i < 16; i++) {
            int l = tid + i * 256;
            int kk = l >> 7;
            int c = l & 127;
            Ws[kk][c] = W[(size_t)(k0 + kk) * HID + c];
        }
        __syncthreads();
#pragma unroll
        for (int kk = 0; kk < 32; ++kk) {
            float4 a  = *(const float4*)(&Xs[kk][ty * 4]);
            float4 b0 = *(const float4*)(&Ws[kk][tx * 8]);
            float4 b1 = *(const float4*)(&Ws[kk][tx * 8 + 4]);
            float av[4] = {a.x, a.y, a.z, a.w};
            float bv[8] = {b0.x, b0.y, b0.z, b0.w, b1.x, b1.y, b1.z, b1.w};
#pragma unroll
            for (int i = 0; i < 4; i++)
#pragma unroll
                for (int j = 0; j < 8; j++)
                    acc[i][j] = fmaf(av[i], bv[j], acc[i][j]);
        }
        __syncthreads();
    }

#pragma unroll
    for (int i = 0; i < 4; i++) {
        int r = row0 + ty * 4 + i;
        if (r < N_NODES) {
            float4 s0 = make_float4(acc[i][0], acc[i][1], acc[i][2], acc[i][3]);
            float4 s1 = make_float4(acc[i][4], acc[i][5], acc[i][6], acc[i][7]);
            *(float4*)(&H[(size_t)r * HID + tx * 8])     = s0;
            *(float4*)(&H[(size_t)r * HID + tx * 8 + 4]) = s1;
        }
    }
}

// ---------------- CSR aggregation layer 1 (+ self loop + bias + relu) ----------------

__global__ __launch_bounds__(256) void k_agg1_csr(const int* __restrict__ rowptr,
                                                  const int* __restrict__ src_s,
                                                  const float* __restrict__ norm_s,
                                                  const float* __restrict__ dinv,
                                                  const float* __restrict__ H1,
                                                  const float* __restrict__ b1,
                                                  float* __restrict__ A1) {
    const int tid = threadIdx.x;
    const int node = blockIdx.x * 2 + (tid >> 7);
    if (node >= N_NODES) return;
    const int c = tid & 127;

    float di = dinv[node];
    float acc = di * di * H1[(size_t)node * HID + c];
    const int beg = rowptr[node];
    const int end = rowptr[node + 1];
    for (int p = beg; p < end; ++p) {
        int s = src_s[p];
        float nm = norm_s[p];
        acc = fmaf(H1[(size_t)s * HID + c], nm, acc);
    }
    A1[(size_t)node * HID + c] = fmaxf(acc + b1[c], 0.0f);
}

// ---------------- GEMM2: H2[50000,40] = A1[50000,128] @ W2[128,40] ----------------

__global__ __launch_bounds__(256) void k_gemm2(const float* __restrict__ A1,
                                               const float* __restrict__ W2,
                                               float* __restrict__ H2) {
    __shared__ float Hs[64][129];
    __shared__ float Ws[128][40];
    const int tid = threadIdx.x;
    const int row0 = blockIdx.x * 64;

    for (int i = tid; i < HID * OUT_C; i += 256) Ws[i / OUT_C][i % OUT_C] = W2[i];
    for (int i = tid; i < 64 * HID; i += 256) {
        int r = i >> 7, k = i & 127;
        int grow = row0 + r;
        Hs[r][k] = (grow < N_NODES) ? A1[(size_t)grow * HID + k] : 0.0f;
    }
    __syncthreads();

    const int r  = tid >> 2;            // 0..63
    const int c0 = (tid & 3) * 10;      // 0,10,20,30
    float acc[10];
#pragma unroll
    for (int j = 0; j < 10; j++) acc[j] = 0.0f;

    for (int k = 0; k < HID; k++) {
        float h = Hs[r][k];
#pragma unroll
        for (int j = 0; j < 10; j++) acc[j] = fmaf(h, Ws[k][c0 + j], acc[j]);
    }

    int grow = row0 + r;
    if (grow < N_NODES) {
#pragma unroll
        for (int j = 0; j < 10; j++) H2[(size_t)grow * OUT_C + c0 + j] = acc[j];
    }
}

// ------- CSR aggregation layer 2 (+ self loop + bias) fused with log_softmax -------

__global__ __launch_bounds__(256) void k_agg2_lsm(const int* __restrict__ rowptr,
                                                  const int* __restrict__ src_s,
                                                  const float* __restrict__ norm_s,
                                                  const float* __restrict__ dinv,
                                                  const float* __restrict__ H2,
                                                  const float* __restrict__ b2,
                                                  float* __restrict__ out) {
    const int tid = threadIdx.x;
    const int node = blockIdx.x * 4 + (tid >> 6);
    if (node >= N_NODES) return;
    const int lane = tid & 63;

    float di = dinv[node];
    float acc = 0.0f;
    if (lane < OUT_C) acc = di * di * H2[(size_t)node * OUT_C + lane];
    const int beg = rowptr[node];
    const int end = rowptr[node + 1];
    for (int p = beg; p < end; ++p) {
        int s = src_s[p];
        float nm = norm_s[p];
        if (lane < OUT_C) acc = fmaf(H2[(size_t)s * OUT_C + lane], nm, acc);
    }
    float v = (lane < OUT_C) ? acc + b2[lane] : -INFINITY;

    float m = v;
#pragma unroll
    for (int off = 32; off > 0; off >>= 1) m = fmaxf(m, __shfl_xor(m, off));
    float ex = (lane < OUT_C) ? __expf(v - m) : 0.0f;
    float s = ex;
#pragma unroll
    for (int off = 32; off > 0; off >>= 1) s += __shfl_xor(s, off);
    if (lane < OUT_C) out[(size_t)node * OUT_C + lane] = v - m - __logf(s);
}

// ---------------- launch ----------------

extern "C" void kernel_launch(void* const* d_in, const int* in_sizes, int n_in,
                              void* d_out, int out_size, void* d_ws, size_t ws_size,
                              hipStream_t stream) {
    const float* x  = (const float*)d_in[0];
    const int*   ei = (const int*)d_in[1];          // [2, E] int32
    const float* ew = (const float*)d_in[2];
    const float* W1 = (const float*)d_in[3];
    const float* b1 = (const float*)d_in[4];
    const float* W2 = (const float*)d_in[5];
    const float* b2 = (const float*)d_in[6];
    float* out = (float*)d_out;

    const int* row = ei;            // sources
    const int* col = ei + E_EDGES;  // targets

    // workspace layout (all 4-byte elems): ~58.3 MB
    float* deg    = (float*)d_ws;                   // N      (dinv in place)
    int*   cnt    = (int*)(deg + N_NODES);          // N      (reused as cursor)
    int*   rowptr = cnt + N_NODES;                  // N+1
    int*   bsum   = rowptr + N_NODES + 1;           // 256
    int*   src_s  = bsum + 256;                     // E
    float* norm_s = (float*)(src_s + E_EDGES);      // E
    float* H1     = norm_s + E_EDGES;               // N*HID
    float* A1     = H1 + (size_t)N_NODES * HID;     // N*HID
    float* H2     = H1;                             // alias: H1 dead after agg1

    const int B = 256;
    int*   cursor = cnt;

    k_init<<<(N_NODES + B - 1) / B, B, 0, stream>>>(deg, cnt);
    k_deg_cnt<<<(E_EDGES + B - 1) / B, B, 0, stream>>>(col, ew, deg, cnt);
    k_dinv<<<(N_NODES + B - 1) / B, B, 0, stream>>>(deg);

    k_scan1<<<SCAN_BLOCKS, B, 0, stream>>>(cnt, rowptr, bsum);
    k_scan2<<<1, B, 0, stream>>>(bsum);
    k_scan3<<<SCAN_BLOCKS, B, 0, stream>>>(rowptr, bsum, cursor);

    k_scatter<<<(E_EDGES + B - 1) / B, B, 0, stream>>>(row, col, ew, deg, cursor,
                                                       src_s, norm_s);

    k_gemm1<<<(N_NODES + 63) / 64, B, 0, stream>>>(x, W1, H1);

    k_agg1_csr<<<(N_NODES + 1) / 2, B, 0, stream>>>(rowptr, src_s, norm_s, deg,
                                                    H1, b1, A1);

    k_gemm2<<<(N_NODES + 63) / 64, B, 0, stream>>>(A1, W2, H2);

    k_agg2_lsm<<<(N_NODES + 3) / 4, B, 0, stream>>>(rowptr, src_s, norm_s, deg,
                                                    H2, b2, out);
}

// Round 3
// 581.801 us; speedup vs baseline: 1.6001x; 1.2539x over previous
//
#include <hip/hip_runtime.h>
#include <math.h>

#define N_NODES 50000
#define F_IN    512
#define HID     128
#define OUT_C   40
#define E_EDGES 800000
#define SCAN_BLOCKS 196   // ceil(50000/256)
#define LDA 40            // padded k-stride (bf16 elems) for MFMA LDS tiles

typedef __attribute__((ext_vector_type(8))) short short8;
typedef __attribute__((ext_vector_type(4))) float f32x4;

__device__ __forceinline__ unsigned short f2bf(float f) {
    union { float f; unsigned u; } v; v.f = f;
    unsigned u = v.u + 0x7fffu + ((v.u >> 16) & 1u);   // RNE
    return (unsigned short)(u >> 16);
}

// ---------------- degree + edge-count ----------------

__global__ void k_init(float* __restrict__ deg, int* __restrict__ cnt) {
    int i = blockIdx.x * blockDim.x + threadIdx.x;
    if (i < N_NODES) { deg[i] = 1.0f; cnt[i] = 0; }   // self-loop weight 1
}

__global__ void k_deg_cnt(const int* __restrict__ col, const float* __restrict__ w,
                          float* __restrict__ deg, int* __restrict__ cnt) {
    int e = blockIdx.x * blockDim.x + threadIdx.x;
    if (e < E_EDGES) {
        int c = col[e];
        atomicAdd(&deg[c], w[e]);
        atomicAdd(&cnt[c], 1);
    }
}

__global__ void k_dinv(float* __restrict__ deg) {
    int i = blockIdx.x * blockDim.x + threadIdx.x;
    if (i < N_NODES) {
        float d = deg[i];
        deg[i] = (d > 0.0f) ? rsqrtf(d) : 0.0f;
    }
}

// ---------------- exclusive scan of cnt -> rowptr (3-stage) ----------------

__global__ __launch_bounds__(256) void k_scan1(const int* __restrict__ cnt,
                                               int* __restrict__ excl,
                                               int* __restrict__ bsum) {
    __shared__ int s[256];
    int tid = threadIdx.x;
    int i = blockIdx.x * 256 + tid;
    int v = (i < N_NODES) ? cnt[i] : 0;
    s[tid] = v;
    __syncthreads();
#pragma unroll
    for (int off = 1; off < 256; off <<= 1) {
        int t = (tid >= off) ? s[tid - off] : 0;
        __syncthreads();
        s[tid] += t;
        __syncthreads();
    }
    if (i < N_NODES) excl[i] = s[tid] - v;
    if (tid == 255) bsum[blockIdx.x] = s[255];
}

__global__ __launch_bounds__(256) void k_scan2(int* __restrict__ bsum) {
    __shared__ int s[256];
    int tid = threadIdx.x;
    int v = (tid < SCAN_BLOCKS) ? bsum[tid] : 0;
    s[tid] = v;
    __syncthreads();
#pragma unroll
    for (int off = 1; off < 256; off <<= 1) {
        int t = (tid >= off) ? s[tid - off] : 0;
        __syncthreads();
        s[tid] += t;
        __syncthreads();
    }
    if (tid < SCAN_BLOCKS) bsum[tid] = s[tid] - v;   // exclusive
}

__global__ __launch_bounds__(256) void k_scan3(int* __restrict__ rowptr,
                                               const int* __restrict__ bsum,
                                               int* __restrict__ cursor) {
    int i = blockIdx.x * 256 + threadIdx.x;
    if (i < N_NODES) {
        int v = rowptr[i] + bsum[blockIdx.x];
        rowptr[i] = v;
        cursor[i] = v;
    }
    if (i == 0) rowptr[N_NODES] = E_EDGES;
}

// ---------------- scatter edges into CSR order (fold norm) ----------------

__global__ void k_scatter(const int* __restrict__ row, const int* __restrict__ col,
                          const float* __restrict__ w, const float* __restrict__ dinv,
                          int* __restrict__ cursor,
                          int* __restrict__ src_s, float* __restrict__ norm_s) {
    int e = blockIdx.x * blockDim.x + threadIdx.x;
    if (e < E_EDGES) {
        int r = row[e], c = col[e];
        float nm = dinv[r] * w[e] * dinv[c];
        int pos = atomicAdd(&cursor[c], 1);
        src_s[pos] = r;
        norm_s[pos] = nm;
    }
}

// ---------------- W1^T -> bf16 prologue: W1bt[n][k] = bf16(W1[k][n]) ----------------

__global__ __launch_bounds__(256) void k_w1t(const float* __restrict__ W1,
                                             unsigned short* __restrict__ W1bt) {
    int idx = blockIdx.x * 256 + threadIdx.x;      // 65536 total
    int k = idx & 511, n = idx >> 9;
    W1bt[(size_t)n * F_IN + k] = f2bf(W1[(size_t)k * HID + n]);
}

// ------- GEMM1 (MFMA bf16): H1[50000,128] = X[50000,512] @ W1[512,128] -------
// 128x128 block tile, 4 waves x (64x64 = 4x4 tiles of 16x16), K-step 32.
// fp32->bf16 conversion fused into A staging; B staged from pre-converted W1bt.

__global__ __launch_bounds__(256) void k_gemm1_mfma(const float* __restrict__ X,
                                                    const unsigned short* __restrict__ W1bt,
                                                    float* __restrict__ H) {
    __shared__ __align__(16) unsigned short As[128 * LDA];
    __shared__ __align__(16) unsigned short Bs[128 * LDA];
    const int tid  = threadIdx.x;
    const int row0 = blockIdx.x * 128;
    const int lane = tid & 63;
    const int w    = tid >> 6;
    const int quad = lane >> 4;
    const int l16  = lane & 15;
    const int wm   = (w >> 1) * 64;
    const int wn   = (w & 1) * 64;

    f32x4 acc[4][4] = {};

    // staging assignment: thread handles row sr (0..127), k-group kg (0 or 16)
    const int sr = tid >> 1;
    const int kg = (tid & 1) * 16;
    int arow = row0 + sr;
    if (arow >= N_NODES) arow = N_NODES - 1;          // clamp: rows are independent
    const float*          xp = X + (size_t)arow * F_IN + kg;
    const unsigned short* bp = W1bt + (size_t)sr * F_IN + kg;
    unsigned short* asw = &As[sr * LDA + kg];
    unsigned short* bsw = &Bs[sr * LDA + kg];

    for (int k0 = 0; k0 < F_IN; k0 += 32) {
        // A: 16 fp32 -> 16 bf16
        float4 xa = *(const float4*)(xp + k0);
        float4 xb = *(const float4*)(xp + k0 + 4);
        float4 xc = *(const float4*)(xp + k0 + 8);
        float4 xd = *(const float4*)(xp + k0 + 12);
        short8 pa, pb;
        pa[0] = (short)f2bf(xa.x); pa[1] = (short)f2bf(xa.y);
        pa[2] = (short)f2bf(xa.z); pa[3] = (short)f2bf(xa.w);
        pa[4] = (short)f2bf(xb.x); pa[5] = (short)f2bf(xb.y);
        pa[6] = (short)f2bf(xb.z); pa[7] = (short)f2bf(xb.w);
        pb[0] = (short)f2bf(xc.x); pb[1] = (short)f2bf(xc.y);
        pb[2] = (short)f2bf(xc.z); pb[3] = (short)f2bf(xc.w);
        pb[4] = (short)f2bf(xd.x); pb[5] = (short)f2bf(xd.y);
        pb[6] = (short)f2bf(xd.z); pb[7] = (short)f2bf(xd.w);
        // B: 16 bf16 passthrough
        short8 wa = *(const short8*)(bp + k0);
        short8 wb = *(const short8*)(bp + k0 + 8);

        *(short8*)(asw)     = pa;
        *(short8*)(asw + 8) = pb;
        *(short8*)(bsw)     = wa;
        *(short8*)(bsw + 8) = wb;
        __syncthreads();

        short8 af[4], bf[4];
#pragma unroll
        for (int i = 0; i < 4; i++)
            af[i] = *(const short8*)&As[(wm + i * 16 + l16) * LDA + quad * 8];
#pragma unroll
        for (int j = 0; j < 4; j++)
            bf[j] = *(const short8*)&Bs[(wn + j * 16 + l16) * LDA + quad * 8];
#pragma unroll
        for (int i = 0; i < 4; i++)
#pragma unroll
            for (int j = 0; j < 4; j++)
                acc[i][j] = __builtin_amdgcn_mfma_f32_16x16x32_bf16(
                    af[i], bf[j], acc[i][j], 0, 0, 0);
        __syncthreads();
    }

#pragma unroll
    for (int i = 0; i < 4; i++) {
#pragma unroll
        for (int r = 0; r < 4; r++) {
            int grow = row0 + wm + i * 16 + quad * 4 + r;
            if (grow < N_NODES) {
#pragma unroll
                for (int j = 0; j < 4; j++) {
                    int gcol = wn + j * 16 + l16;
                    H[(size_t)grow * HID + gcol] = acc[i][j][r];
                }
            }
        }
    }
}

// ---------------- CSR aggregation layer 1 (+ self loop + bias + relu) ----------------

__global__ __launch_bounds__(256) void k_agg1_csr(const int* __restrict__ rowptr,
                                                  const int* __restrict__ src_s,
                                                  const float* __restrict__ norm_s,
                                                  const float* __restrict__ dinv,
                                                  const float* __restrict__ H1,
                                                  const float* __restrict__ b1,
                                                  float* __restrict__ A1) {
    const int tid = threadIdx.x;
    const int node = blockIdx.x * 2 + (tid >> 7);
    if (node >= N_NODES) return;
    const int c = tid & 127;

    float di = dinv[node];
    float acc = di * di * H1[(size_t)node * HID + c];
    const int beg = rowptr[node];
    const int end = rowptr[node + 1];
    for (int p = beg; p < end; ++p) {
        int s = src_s[p];
        float nm = norm_s[p];
        acc = fmaf(H1[(size_t)s * HID + c], nm, acc);
    }
    A1[(size_t)node * HID + c] = fmaxf(acc + b1[c], 0.0f);
}

// ---------------- GEMM2: H2[50000,40] = A1[50000,128] @ W2[128,40] ----------------

__global__ __launch_bounds__(256) void k_gemm2(const float* __restrict__ A1,
                                               const float* __restrict__ W2,
                                               float* __restrict__ H2) {
    __shared__ float Hs[64][129];
    __shared__ float Ws[128][40];
    const int tid = threadIdx.x;
    const int row0 = blockIdx.x * 64;

    for (int i = tid; i < HID * OUT_C; i += 256) Ws[i / OUT_C][i % OUT_C] = W2[i];
    for (int i = tid; i < 64 * HID; i += 256) {
        int r = i >> 7, k = i & 127;
        int grow = row0 + r;
        Hs[r][k] = (grow < N_NODES) ? A1[(size_t)grow * HID + k] : 0.0f;
    }
    __syncthreads();

    const int r  = tid >> 2;            // 0..63
    const int c0 = (tid & 3) * 10;      // 0,10,20,30
    float acc[10];
#pragma unroll
    for (int j = 0; j < 10; j++) acc[j] = 0.0f;

    for (int k = 0; k < HID; k++) {
        float h = Hs[r][k];
#pragma unroll
        for (int j = 0; j < 10; j++) acc[j] = fmaf(h, Ws[k][c0 + j], acc[j]);
    }

    int grow = row0 + r;
    if (grow < N_NODES) {
#pragma unroll
        for (int j = 0; j < 10; j++) H2[(size_t)grow * OUT_C + c0 + j] = acc[j];
    }
}

// ------- CSR aggregation layer 2 (+ self loop + bias) fused with log_softmax -------

__global__ __launch_bounds__(256) void k_agg2_lsm(const int* __restrict__ rowptr,
                                                  const int* __restrict__ src_s,
                                                  const float* __restrict__ norm_s,
                                                  const float* __restrict__ dinv,
                                                  const float* __restrict__ H2,
                                                  const float* __restrict__ b2,
                                                  float* __restrict__ out) {
    const int tid = threadIdx.x;
    const int node = blockIdx.x * 4 + (tid >> 6);
    if (node >= N_NODES) return;
    const int lane = tid & 63;

    float di = dinv[node];
    float acc = 0.0f;
    if (lane < OUT_C) acc = di * di * H2[(size_t)node * OUT_C + lane];
    const int beg = rowptr[node];
    const int end = rowptr[node + 1];
    for (int p = beg; p < end; ++p) {
        int s = src_s[p];
        float nm = norm_s[p];
        if (lane < OUT_C) acc = fmaf(H2[(size_t)s * OUT_C + lane], nm, acc);
    }
    float v = (lane < OUT_C) ? acc + b2[lane] : -INFINITY;

    float m = v;
#pragma unroll
    for (int off = 32; off > 0; off >>= 1) m = fmaxf(m, __shfl_xor(m, off));
    float ex = (lane < OUT_C) ? __expf(v - m) : 0.0f;
    float s = ex;
#pragma unroll
    for (int off = 32; off > 0; off >>= 1) s += __shfl_xor(s, off);
    if (lane < OUT_C) out[(size_t)node * OUT_C + lane] = v - m - __logf(s);
}

// ---------------- launch ----------------

extern "C" void kernel_launch(void* const* d_in, const int* in_sizes, int n_in,
                              void* d_out, int out_size, void* d_ws, size_t ws_size,
                              hipStream_t stream) {
    const float* x  = (const float*)d_in[0];
    const int*   ei = (const int*)d_in[1];          // [2, E] int32
    const float* ew = (const float*)d_in[2];
    const float* W1 = (const float*)d_in[3];
    const float* b1 = (const float*)d_in[4];
    const float* W2 = (const float*)d_in[5];
    const float* b2 = (const float*)d_in[6];
    float* out = (float*)d_out;

    const int* row = ei;            // sources
    const int* col = ei + E_EDGES;  // targets

    // workspace layout (float offsets, padded for 16B alignment): ~58.3 MB
    float* ws     = (float*)d_ws;
    float* deg    = ws;                               // [0, 50000)
    int*   cnt    = (int*)(ws + 50000);               // [50000, 100000)
    int*   rowptr = (int*)(ws + 100000);              // [100000, 150001)
    int*   bsum   = (int*)(ws + 150016);              // [150016, 150272)
    int*   src_s  = (int*)(ws + 150272);              // [150272, 950272)
    float* norm_s = ws + 950272;                      // [950272, 1750272)
    float* H1     = ws + 1750272;                     // N*HID (16B aligned)
    float* A1     = H1 + (size_t)N_NODES * HID;       // N*HID
    unsigned short* W1bt = (unsigned short*)(A1 + (size_t)N_NODES * HID); // 128*512
    float* H2     = H1;                               // alias: H1 dead after agg1

    const int B = 256;
    int* cursor = cnt;

    k_init<<<(N_NODES + B - 1) / B, B, 0, stream>>>(deg, cnt);
    k_deg_cnt<<<(E_EDGES + B - 1) / B, B, 0, stream>>>(col, ew, deg, cnt);
    k_dinv<<<(N_NODES + B - 1) / B, B, 0, stream>>>(deg);

    k_scan1<<<SCAN_BLOCKS, B, 0, stream>>>(cnt, rowptr, bsum);
    k_scan2<<<1, B, 0, stream>>>(bsum);
    k_scan3<<<SCAN_BLOCKS, B, 0, stream>>>(rowptr, bsum, cursor);

    k_scatter<<<(E_EDGES + B - 1) / B, B, 0, stream>>>(row, col, ew, deg, cursor,
                                                       src_s, norm_s);

    k_w1t<<<(F_IN * HID) / B, B, 0, stream>>>(W1, W1bt);
    k_gemm1_mfma<<<(N_NODES + 127) / 128, B, 0, stream>>>(x, W1bt, H1);

    k_agg1_csr<<<(N_NODES + 1) / 2, B, 0, stream>>>(rowptr, src_s, norm_s, deg,
                                                    H1, b1, A1);

    k_gemm2<<<(N_NODES + 63) / 64, B, 0, stream>>>(A1, W2, H2);

    k_agg2_lsm<<<(N_NODES + 3) / 4, B, 0, stream>>>(rowptr, src_s, norm_s, deg,
                                                    H2, b2, out);
}

// Round 4
// 444.747 us; speedup vs baseline: 2.0932x; 1.3082x over previous
//
#include <hip/hip_runtime.h>
#include <math.h>

#define N_NODES 50000
#define F_IN    512
#define HID     128
#define OUT_C   40
#define E_EDGES 800000
#define SCAN_BLOCKS 196   // ceil(50000/256)
#define LDA 40            // padded k-stride (bf16 elems) for MFMA LDS tiles
#define MAXDEG 96         // LDS edge-stage capacity per node (max in-degree ~35)

typedef __attribute__((ext_vector_type(8))) short short8;
typedef __attribute__((ext_vector_type(4))) float f32x4;

__device__ __forceinline__ unsigned short f2bf(float f) {
    union { float f; unsigned u; } v; v.f = f;
    unsigned u = v.u + 0x7fffu + ((v.u >> 16) & 1u);   // RNE
    return (unsigned short)(u >> 16);
}

// ---------------- degree + edge-count ----------------

__global__ void k_init(float* __restrict__ deg, int* __restrict__ cnt) {
    int i = blockIdx.x * blockDim.x + threadIdx.x;
    if (i < N_NODES) { deg[i] = 1.0f; cnt[i] = 0; }   // self-loop weight 1
}

__global__ void k_deg_cnt(const int* __restrict__ col, const float* __restrict__ w,
                          float* __restrict__ deg, int* __restrict__ cnt) {
    int e = blockIdx.x * blockDim.x + threadIdx.x;
    if (e < E_EDGES) {
        int c = col[e];
        atomicAdd(&deg[c], w[e]);
        atomicAdd(&cnt[c], 1);
    }
}

__global__ void k_dinv(float* __restrict__ deg) {
    int i = blockIdx.x * blockDim.x + threadIdx.x;
    if (i < N_NODES) {
        float d = deg[i];
        deg[i] = (d > 0.0f) ? rsqrtf(d) : 0.0f;
    }
}

// ---------------- exclusive scan of cnt -> rowptr (3-stage) ----------------

__global__ __launch_bounds__(256) void k_scan1(const int* __restrict__ cnt,
                                               int* __restrict__ excl,
                                               int* __restrict__ bsum) {
    __shared__ int s[256];
    int tid = threadIdx.x;
    int i = blockIdx.x * 256 + tid;
    int v = (i < N_NODES) ? cnt[i] : 0;
    s[tid] = v;
    __syncthreads();
#pragma unroll
    for (int off = 1; off < 256; off <<= 1) {
        int t = (tid >= off) ? s[tid - off] : 0;
        __syncthreads();
        s[tid] += t;
        __syncthreads();
    }
    if (i < N_NODES) excl[i] = s[tid] - v;
    if (tid == 255) bsum[blockIdx.x] = s[255];
}

__global__ __launch_bounds__(256) void k_scan2(int* __restrict__ bsum) {
    __shared__ int s[256];
    int tid = threadIdx.x;
    int v = (tid < SCAN_BLOCKS) ? bsum[tid] : 0;
    s[tid] = v;
    __syncthreads();
#pragma unroll
    for (int off = 1; off < 256; off <<= 1) {
        int t = (tid >= off) ? s[tid - off] : 0;
        __syncthreads();
        s[tid] += t;
        __syncthreads();
    }
    if (tid < SCAN_BLOCKS) bsum[tid] = s[tid] - v;   // exclusive
}

__global__ __launch_bounds__(256) void k_scan3(int* __restrict__ rowptr,
                                               const int* __restrict__ bsum,
                                               int* __restrict__ cursor) {
    int i = blockIdx.x * 256 + threadIdx.x;
    if (i < N_NODES) {
        int v = rowptr[i] + bsum[blockIdx.x];
        rowptr[i] = v;
        cursor[i] = v;
    }
    if (i == 0) rowptr[N_NODES] = E_EDGES;
}

// ---------------- scatter edges into CSR order (fold norm) ----------------

__global__ void k_scatter(const int* __restrict__ row, const int* __restrict__ col,
                          const float* __restrict__ w, const float* __restrict__ dinv,
                          int* __restrict__ cursor,
                          int* __restrict__ src_s, float* __restrict__ norm_s) {
    int e = blockIdx.x * blockDim.x + threadIdx.x;
    if (e < E_EDGES) {
        int r = row[e], c = col[e];
        float nm = dinv[r] * w[e] * dinv[c];
        int pos = atomicAdd(&cursor[c], 1);
        src_s[pos] = r;
        norm_s[pos] = nm;
    }
}

// ---------------- W1^T -> bf16 prologue: W1bt[n][k] = bf16(W1[k][n]) ----------------

__global__ __launch_bounds__(256) void k_w1t(const float* __restrict__ W1,
                                             unsigned short* __restrict__ W1bt) {
    int idx = blockIdx.x * 256 + threadIdx.x;      // 65536 total
    int k = idx & 511, n = idx >> 9;
    W1bt[(size_t)n * F_IN + k] = f2bf(W1[(size_t)k * HID + n]);
}

// ------- GEMM1 (MFMA bf16): H1[50000,128] = X[50000,512] @ W1[512,128] -------

__global__ __launch_bounds__(256) void k_gemm1_mfma(const float* __restrict__ X,
                                                    const unsigned short* __restrict__ W1bt,
                                                    float* __restrict__ H) {
    __shared__ __align__(16) unsigned short As[128 * LDA];
    __shared__ __align__(16) unsigned short Bs[128 * LDA];
    const int tid  = threadIdx.x;
    const int row0 = blockIdx.x * 128;
    const int lane = tid & 63;
    const int w    = tid >> 6;
    const int quad = lane >> 4;
    const int l16  = lane & 15;
    const int wm   = (w >> 1) * 64;
    const int wn   = (w & 1) * 64;

    f32x4 acc[4][4] = {};

    const int sr = tid >> 1;
    const int kg = (tid & 1) * 16;
    int arow = row0 + sr;
    if (arow >= N_NODES) arow = N_NODES - 1;          // clamp: rows are independent
    const float*          xp = X + (size_t)arow * F_IN + kg;
    const unsigned short* bp = W1bt + (size_t)sr * F_IN + kg;
    unsigned short* asw = &As[sr * LDA + kg];
    unsigned short* bsw = &Bs[sr * LDA + kg];

    for (int k0 = 0; k0 < F_IN; k0 += 32) {
        float4 xa = *(const float4*)(xp + k0);
        float4 xb = *(const float4*)(xp + k0 + 4);
        float4 xc = *(const float4*)(xp + k0 + 8);
        float4 xd = *(const float4*)(xp + k0 + 12);
        short8 pa, pb;
        pa[0] = (short)f2bf(xa.x); pa[1] = (short)f2bf(xa.y);
        pa[2] = (short)f2bf(xa.z); pa[3] = (short)f2bf(xa.w);
        pa[4] = (short)f2bf(xb.x); pa[5] = (short)f2bf(xb.y);
        pa[6] = (short)f2bf(xb.z); pa[7] = (short)f2bf(xb.w);
        pb[0] = (short)f2bf(xc.x); pb[1] = (short)f2bf(xc.y);
        pb[2] = (short)f2bf(xc.z); pb[3] = (short)f2bf(xc.w);
        pb[4] = (short)f2bf(xd.x); pb[5] = (short)f2bf(xd.y);
        pb[6] = (short)f2bf(xd.z); pb[7] = (short)f2bf(xd.w);
        short8 wa = *(const short8*)(bp + k0);
        short8 wb = *(const short8*)(bp + k0 + 8);

        *(short8*)(asw)     = pa;
        *(short8*)(asw + 8) = pb;
        *(short8*)(bsw)     = wa;
        *(short8*)(bsw + 8) = wb;
        __syncthreads();

        short8 af[4], bf[4];
#pragma unroll
        for (int i = 0; i < 4; i++)
            af[i] = *(const short8*)&As[(wm + i * 16 + l16) * LDA + quad * 8];
#pragma unroll
        for (int j = 0; j < 4; j++)
            bf[j] = *(const short8*)&Bs[(wn + j * 16 + l16) * LDA + quad * 8];
#pragma unroll
        for (int i = 0; i < 4; i++)
#pragma unroll
            for (int j = 0; j < 4; j++)
                acc[i][j] = __builtin_amdgcn_mfma_f32_16x16x32_bf16(
                    af[i], bf[j], acc[i][j], 0, 0, 0);
        __syncthreads();
    }

#pragma unroll
    for (int i = 0; i < 4; i++) {
#pragma unroll
        for (int r = 0; r < 4; r++) {
            int grow = row0 + wm + i * 16 + quad * 4 + r;
            if (grow < N_NODES) {
#pragma unroll
                for (int j = 0; j < 4; j++) {
                    int gcol = wn + j * 16 + l16;
                    H[(size_t)grow * HID + gcol] = acc[i][j][r];
                }
            }
        }
    }
}

// ------- CSR aggregation layer 1 (+ self loop + bias + relu), 8-wide gathers -------
// 2 nodes/block (128 threads each). Edge indices staged in LDS, padded to x8 with
// zero-weight dummies so the gather loop is fully batched (8 loads in flight).

__global__ __launch_bounds__(256) void k_agg1_csr(const int* __restrict__ rowptr,
                                                  const int* __restrict__ src_s,
                                                  const float* __restrict__ norm_s,
                                                  const float* __restrict__ dinv,
                                                  const float* __restrict__ H1,
                                                  const float* __restrict__ b1,
                                                  float* __restrict__ A1) {
    __shared__ int   sS[2][MAXDEG];
    __shared__ float sN[2][MAXDEG];
    const int tid = threadIdx.x;
    const int h   = tid >> 7;
    const int c   = tid & 127;
    const int node = blockIdx.x * 2 + h;

    int beg = 0, d = 0;
    if (node < N_NODES) {
        beg = rowptr[node];
        d   = rowptr[node + 1] - beg;
    }
    const int dl = (d < MAXDEG) ? d : MAXDEG;
    const int dp = (dl + 7) & ~7;
    for (int p = c; p < dp; p += 128) {
        bool in = p < dl;
        sS[h][p] = in ? src_s[beg + p] : 0;
        sN[h][p] = in ? norm_s[beg + p] : 0.0f;
    }
    __syncthreads();
    if (node >= N_NODES) return;

    float di = dinv[node];
    float a0 = di * di * H1[(size_t)node * HID + c];
    float a1 = 0.0f, a2 = 0.0f, a3 = 0.0f;

    for (int p = 0; p < dp; p += 8) {
        int   s[8]; float n[8], v[8];
#pragma unroll
        for (int j = 0; j < 8; j++) { s[j] = sS[h][p + j]; n[j] = sN[h][p + j]; }
#pragma unroll
        for (int j = 0; j < 8; j++) v[j] = H1[(size_t)s[j] * HID + c];
        a0 = fmaf(v[0], n[0], a0);  a1 = fmaf(v[1], n[1], a1);
        a2 = fmaf(v[2], n[2], a2);  a3 = fmaf(v[3], n[3], a3);
        a0 = fmaf(v[4], n[4], a0);  a1 = fmaf(v[5], n[5], a1);
        a2 = fmaf(v[6], n[6], a2);  a3 = fmaf(v[7], n[7], a3);
    }
    for (int q = dl; q < d; ++q)   // overflow fallback (never hit in practice)
        a0 = fmaf(H1[(size_t)src_s[beg + q] * HID + c], norm_s[beg + q], a0);

    float acc = (a0 + a1) + (a2 + a3);
    A1[(size_t)node * HID + c] = fmaxf(acc + b1[c], 0.0f);
}

// ---------------- GEMM2: H2[50000,40] = A1[50000,128] @ W2[128,40] ----------------

__global__ __launch_bounds__(256) void k_gemm2(const float* __restrict__ A1,
                                               const float* __restrict__ W2,
                                               float* __restrict__ H2) {
    __shared__ float Hs[64][129];
    __shared__ float Ws[128][40];
    const int tid = threadIdx.x;
    const int row0 = blockIdx.x * 64;

    for (int i = tid; i < HID * OUT_C; i += 256) Ws[i / OUT_C][i % OUT_C] = W2[i];
    for (int i = tid; i < 64 * HID; i += 256) {
        int r = i >> 7, k = i & 127;
        int grow = row0 + r;
        Hs[r][k] = (grow < N_NODES) ? A1[(size_t)grow * HID + k] : 0.0f;
    }
    __syncthreads();

    const int r  = tid >> 2;            // 0..63
    const int c0 = (tid & 3) * 10;      // 0,10,20,30
    float acc[10];
#pragma unroll
    for (int j = 0; j < 10; j++) acc[j] = 0.0f;

    for (int k = 0; k < HID; k++) {
        float h = Hs[r][k];
#pragma unroll
        for (int j = 0; j < 10; j++) acc[j] = fmaf(h, Ws[k][c0 + j], acc[j]);
    }

    int grow = row0 + r;
    if (grow < N_NODES) {
#pragma unroll
        for (int j = 0; j < 10; j++) H2[(size_t)grow * OUT_C + c0 + j] = acc[j];
    }
}

// ------- CSR aggregation layer 2 (+ self loop + bias) fused with log_softmax -------
// 4 nodes/block, wave per node (LDS regions wave-private: no barrier needed).

__global__ __launch_bounds__(256) void k_agg2_lsm(const int* __restrict__ rowptr,
                                                  const int* __restrict__ src_s,
                                                  const float* __restrict__ norm_s,
                                                  const float* __restrict__ dinv,
                                                  const float* __restrict__ H2,
                                                  const float* __restrict__ b2,
                                                  float* __restrict__ out) {
    __shared__ int   sS[4][MAXDEG];
    __shared__ float sN[4][MAXDEG];
    const int tid  = threadIdx.x;
    const int wv   = tid >> 6;
    const int lane = tid & 63;
    const int node = blockIdx.x * 4 + wv;
    if (node >= N_NODES) return;

    const int beg = rowptr[node];
    const int d   = rowptr[node + 1] - beg;
    const int dl = (d < MAXDEG) ? d : MAXDEG;
    const int dp = (dl + 7) & ~7;
    for (int p = lane; p < dp; p += 64) {
        bool in = p < dl;
        sS[wv][p] = in ? src_s[beg + p] : 0;
        sN[wv][p] = in ? norm_s[beg + p] : 0.0f;
    }
    // wave-private LDS: compiler inserts lgkmcnt wait; no __syncthreads needed

    float di = dinv[node];
    float a0 = 0.0f, a1 = 0.0f, a2 = 0.0f, a3 = 0.0f;
    if (lane < OUT_C) a0 = di * di * H2[(size_t)node * OUT_C + lane];

    for (int p = 0; p < dp; p += 8) {
        int   s[8]; float n[8], v[8];
#pragma unroll
        for (int j = 0; j < 8; j++) { s[j] = sS[wv][p + j]; n[j] = sN[wv][p + j]; }
#pragma unroll
        for (int j = 0; j < 8; j++)
            v[j] = (lane < OUT_C) ? H2[(size_t)s[j] * OUT_C + lane] : 0.0f;
        a0 = fmaf(v[0], n[0], a0);  a1 = fmaf(v[1], n[1], a1);
        a2 = fmaf(v[2], n[2], a2);  a3 = fmaf(v[3], n[3], a3);
        a0 = fmaf(v[4], n[4], a0);  a1 = fmaf(v[5], n[5], a1);
        a2 = fmaf(v[6], n[6], a2);  a3 = fmaf(v[7], n[7], a3);
    }
    for (int q = dl; q < d; ++q)   // overflow fallback
        if (lane < OUT_C)
            a0 = fmaf(H2[(size_t)src_s[beg + q] * OUT_C + lane], norm_s[beg + q], a0);

    float acc = (a0 + a1) + (a2 + a3);
    float v = (lane < OUT_C) ? acc + b2[lane] : -INFINITY;

    float m = v;
#pragma unroll
    for (int off = 32; off > 0; off >>= 1) m = fmaxf(m, __shfl_xor(m, off));
    float ex = (lane < OUT_C) ? __expf(v - m) : 0.0f;
    float s = ex;
#pragma unroll
    for (int off = 32; off > 0; off >>= 1) s += __shfl_xor(s, off);
    if (lane < OUT_C) out[(size_t)node * OUT_C + lane] = v - m - __logf(s);
}

// ---------------- launch ----------------

extern "C" void kernel_launch(void* const* d_in, const int* in_sizes, int n_in,
                              void* d_out, int out_size, void* d_ws, size_t ws_size,
                              hipStream_t stream) {
    const float* x  = (const float*)d_in[0];
    const int*   ei = (const int*)d_in[1];          // [2, E] int32
    const float* ew = (const float*)d_in[2];
    const float* W1 = (const float*)d_in[3];
    const float* b1 = (const float*)d_in[4];
    const float* W2 = (const float*)d_in[5];
    const float* b2 = (const float*)d_in[6];
    float* out = (float*)d_out;

    const int* row = ei;            // sources
    const int* col = ei + E_EDGES;  // targets

    float* ws     = (float*)d_ws;
    float* deg    = ws;                               // [0, 50000)
    int*   cnt    = (int*)(ws + 50000);               // [50000, 100000)
    int*   rowptr = (int*)(ws + 100000);              // [100000, 150001)
    int*   bsum   = (int*)(ws + 150016);              // [150016, 150272)
    int*   src_s  = (int*)(ws + 150272);              // [150272, 950272)
    float* norm_s = ws + 950272;                      // [950272, 1750272)
    float* H1     = ws + 1750272;                     // N*HID (16B aligned)
    float* A1     = H1 + (size_t)N_NODES * HID;       // N*HID
    unsigned short* W1bt = (unsigned short*)(A1 + (size_t)N_NODES * HID); // 128*512
    float* H2     = H1;                               // alias: H1 dead after agg1

    const int B = 256;
    int* cursor = cnt;

    k_init<<<(N_NODES + B - 1) / B, B, 0, stream>>>(deg, cnt);
    k_deg_cnt<<<(E_EDGES + B - 1) / B, B, 0, stream>>>(col, ew, deg, cnt);
    k_dinv<<<(N_NODES + B - 1) / B, B, 0, stream>>>(deg);

    k_scan1<<<SCAN_BLOCKS, B, 0, stream>>>(cnt, rowptr, bsum);
    k_scan2<<<1, B, 0, stream>>>(bsum);
    k_scan3<<<SCAN_BLOCKS, B, 0, stream>>>(rowptr, bsum, cursor);

    k_scatter<<<(E_EDGES + B - 1) / B, B, 0, stream>>>(row, col, ew, deg, cursor,
                                                       src_s, norm_s);

    k_w1t<<<(F_IN * HID) / B, B, 0, stream>>>(W1, W1bt);
    k_gemm1_mfma<<<(N_NODES + 127) / 128, B, 0, stream>>>(x, W1bt, H1);

    k_agg1_csr<<<(N_NODES + 1) / 2, B, 0, stream>>>(rowptr, src_s, norm_s, deg,
                                                    H1, b1, A1);

    k_gemm2<<<(N_NODES + 63) / 64, B, 0, stream>>>(A1, W2, H2);

    k_agg2_lsm<<<(N_NODES + 3) / 4, B, 0, stream>>>(rowptr, src_s, norm_s, deg,
                                                    H2, b2, out);
}

// Round 5
// 384.128 us; speedup vs baseline: 2.4235x; 1.1578x over previous
//
#include <hip/hip_runtime.h>
#include <math.h>

#define N_NODES 50000
#define F_IN    512
#define HID     128
#define OUT_C   40
#define E_EDGES 800000
#define SCAN_BLOCKS 196   // ceil(50000/256)
#define LDA 40            // padded k-stride (bf16 elems) for MFMA LDS tiles
#define MAXDEG 96         // LDS edge-stage capacity per node (max in-degree ~35)

typedef __attribute__((ext_vector_type(8))) short short8;
typedef __attribute__((ext_vector_type(4))) float f32x4;

__device__ __forceinline__ unsigned short f2bf(float f) {
    union { float f; unsigned u; } v; v.f = f;
    unsigned u = v.u + 0x7fffu + ((v.u >> 16) & 1u);   // RNE
    return (unsigned short)(u >> 16);
}

// -------- packed degree/count histogram: [63:40]=count, [39:0]=sum(w)*2^32 --------

__global__ void k_init(unsigned long long* __restrict__ packed) {
    int i = blockIdx.x * blockDim.x + threadIdx.x;
    if (i < N_NODES) packed[i] = 0ULL;
}

__global__ void k_deg_cnt_rank(const int* __restrict__ col, const float* __restrict__ w,
                               unsigned long long* __restrict__ packed,
                               int* __restrict__ rank) {
    int e = blockIdx.x * blockDim.x + threadIdx.x;
    if (e < E_EDGES) {
        int c = col[e];
        unsigned long long fx = (unsigned long long)(w[e] * 4294967296.0f);
        unsigned long long old = atomicAdd(&packed[c], (1ULL << 40) | fx);
        rank[e] = (int)(old >> 40);     // #earlier edges with same target = rank
    }
}

__global__ void k_dinv(const unsigned long long* __restrict__ packed,
                       float* __restrict__ dinv) {
    int i = blockIdx.x * blockDim.x + threadIdx.x;
    if (i < N_NODES) {
        float d = 1.0f + (float)(packed[i] & 0xFFFFFFFFFFULL) * (1.0f / 4294967296.0f);
        dinv[i] = rsqrtf(d);    // d >= 1 always (self-loop)
    }
}

// ---------------- exclusive scan of counts -> rowptr (3-stage) ----------------

__global__ __launch_bounds__(256) void k_scan1(const unsigned long long* __restrict__ packed,
                                               int* __restrict__ excl,
                                               int* __restrict__ bsum) {
    __shared__ int s[256];
    int tid = threadIdx.x;
    int i = blockIdx.x * 256 + tid;
    int v = (i < N_NODES) ? (int)(packed[i] >> 40) : 0;
    s[tid] = v;
    __syncthreads();
#pragma unroll
    for (int off = 1; off < 256; off <<= 1) {
        int t = (tid >= off) ? s[tid - off] : 0;
        __syncthreads();
        s[tid] += t;
        __syncthreads();
    }
    if (i < N_NODES) excl[i] = s[tid] - v;
    if (tid == 255) bsum[blockIdx.x] = s[255];
}

__global__ __launch_bounds__(256) void k_scan2(int* __restrict__ bsum) {
    __shared__ int s[256];
    int tid = threadIdx.x;
    int v = (tid < SCAN_BLOCKS) ? bsum[tid] : 0;
    s[tid] = v;
    __syncthreads();
#pragma unroll
    for (int off = 1; off < 256; off <<= 1) {
        int t = (tid >= off) ? s[tid - off] : 0;
        __syncthreads();
        s[tid] += t;
        __syncthreads();
    }
    if (tid < SCAN_BLOCKS) bsum[tid] = s[tid] - v;   // exclusive
}

__global__ __launch_bounds__(256) void k_scan3(int* __restrict__ rowptr,
                                               const int* __restrict__ bsum) {
    int i = blockIdx.x * 256 + threadIdx.x;
    if (i < N_NODES) rowptr[i] += bsum[blockIdx.x];
    if (i == 0) rowptr[N_NODES] = E_EDGES;
}

// ------- scatter edges into CSR order, atomic-free; fold pre=dinv[src]*w -------

__global__ void k_scatter(const int* __restrict__ row, const int* __restrict__ col,
                          const float* __restrict__ w, const float* __restrict__ dinv,
                          const int* __restrict__ rowptr, const int* __restrict__ rank,
                          int2* __restrict__ es) {
    int e = blockIdx.x * blockDim.x + threadIdx.x;
    if (e < E_EDGES) {
        int r = row[e], c = col[e];
        float pre = dinv[r] * w[e];
        int pos = rowptr[c] + rank[e];
        es[pos] = make_int2(r, __float_as_int(pre));
    }
}

// ---------------- W1^T -> bf16 prologue: W1bt[n][k] = bf16(W1[k][n]) ----------------

__global__ __launch_bounds__(256) void k_w1t(const float* __restrict__ W1,
                                             unsigned short* __restrict__ W1bt) {
    int idx = blockIdx.x * 256 + threadIdx.x;      // 65536 total
    int k = idx & 511, n = idx >> 9;
    W1bt[(size_t)n * F_IN + k] = f2bf(W1[(size_t)k * HID + n]);
}

// ------- GEMM1 (MFMA bf16): H1[50000,128] = X[50000,512] @ W1[512,128] -------

__global__ __launch_bounds__(256) void k_gemm1_mfma(const float* __restrict__ X,
                                                    const unsigned short* __restrict__ W1bt,
                                                    float* __restrict__ H) {
    __shared__ __align__(16) unsigned short As[128 * LDA];
    __shared__ __align__(16) unsigned short Bs[128 * LDA];
    const int tid  = threadIdx.x;
    const int row0 = blockIdx.x * 128;
    const int lane = tid & 63;
    const int w    = tid >> 6;
    const int quad = lane >> 4;
    const int l16  = lane & 15;
    const int wm   = (w >> 1) * 64;
    const int wn   = (w & 1) * 64;

    f32x4 acc[4][4] = {};

    const int sr = tid >> 1;
    const int kg = (tid & 1) * 16;
    int arow = row0 + sr;
    if (arow >= N_NODES) arow = N_NODES - 1;          // clamp: rows are independent
    const float*          xp = X + (size_t)arow * F_IN + kg;
    const unsigned short* bp = W1bt + (size_t)sr * F_IN + kg;
    unsigned short* asw = &As[sr * LDA + kg];
    unsigned short* bsw = &Bs[sr * LDA + kg];

    for (int k0 = 0; k0 < F_IN; k0 += 32) {
        float4 xa = *(const float4*)(xp + k0);
        float4 xb = *(const float4*)(xp + k0 + 4);
        float4 xc = *(const float4*)(xp + k0 + 8);
        float4 xd = *(const float4*)(xp + k0 + 12);
        short8 pa, pb;
        pa[0] = (short)f2bf(xa.x); pa[1] = (short)f2bf(xa.y);
        pa[2] = (short)f2bf(xa.z); pa[3] = (short)f2bf(xa.w);
        pa[4] = (short)f2bf(xb.x); pa[5] = (short)f2bf(xb.y);
        pa[6] = (short)f2bf(xb.z); pa[7] = (short)f2bf(xb.w);
        pb[0] = (short)f2bf(xc.x); pb[1] = (short)f2bf(xc.y);
        pb[2] = (short)f2bf(xc.z); pb[3] = (short)f2bf(xc.w);
        pb[4] = (short)f2bf(xd.x); pb[5] = (short)f2bf(xd.y);
        pb[6] = (short)f2bf(xd.z); pb[7] = (short)f2bf(xd.w);
        short8 wa = *(const short8*)(bp + k0);
        short8 wb = *(const short8*)(bp + k0 + 8);

        *(short8*)(asw)     = pa;
        *(short8*)(asw + 8) = pb;
        *(short8*)(bsw)     = wa;
        *(short8*)(bsw + 8) = wb;
        __syncthreads();

        short8 af[4], bf[4];
#pragma unroll
        for (int i = 0; i < 4; i++)
            af[i] = *(const short8*)&As[(wm + i * 16 + l16) * LDA + quad * 8];
#pragma unroll
        for (int j = 0; j < 4; j++)
            bf[j] = *(const short8*)&Bs[(wn + j * 16 + l16) * LDA + quad * 8];
#pragma unroll
        for (int i = 0; i < 4; i++)
#pragma unroll
            for (int j = 0; j < 4; j++)
                acc[i][j] = __builtin_amdgcn_mfma_f32_16x16x32_bf16(
                    af[i], bf[j], acc[i][j], 0, 0, 0);
        __syncthreads();
    }

#pragma unroll
    for (int i = 0; i < 4; i++) {
#pragma unroll
        for (int r = 0; r < 4; r++) {
            int grow = row0 + wm + i * 16 + quad * 4 + r;
            if (grow < N_NODES) {
#pragma unroll
                for (int j = 0; j < 4; j++) {
                    int gcol = wn + j * 16 + l16;
                    H[(size_t)grow * HID + gcol] = acc[i][j][r];
                }
            }
        }
    }
}

// ------- CSR aggregation layer 1: relu(di*(sum pre*H1[s] + di*H1[n]) + b1) -------

__global__ __launch_bounds__(256) void k_agg1_csr(const int* __restrict__ rowptr,
                                                  const int2* __restrict__ es,
                                                  const float* __restrict__ dinv,
                                                  const float* __restrict__ H1,
                                                  const float* __restrict__ b1,
                                                  float* __restrict__ A1) {
    __shared__ int2 sE[2][MAXDEG];
    const int tid = threadIdx.x;
    const int h   = tid >> 7;
    const int c   = tid & 127;
    const int node = blockIdx.x * 2 + h;

    int beg = 0, d = 0;
    if (node < N_NODES) {
        beg = rowptr[node];
        d   = rowptr[node + 1] - beg;
    }
    const int dl = (d < MAXDEG) ? d : MAXDEG;
    const int dp = (dl + 7) & ~7;
    for (int p = c; p < dp; p += 128)
        sE[h][p] = (p < dl) ? es[beg + p] : make_int2(0, 0);
    __syncthreads();
    if (node >= N_NODES) return;

    float di = dinv[node];
    float a0 = di * H1[(size_t)node * HID + c];
    float a1 = 0.0f, a2 = 0.0f, a3 = 0.0f;

    for (int p = 0; p < dp; p += 8) {
        int s[8]; float n[8], v[8];
#pragma unroll
        for (int j = 0; j < 8; j++) {
            int2 t = sE[h][p + j];
            s[j] = t.x; n[j] = __int_as_float(t.y);
        }
#pragma unroll
        for (int j = 0; j < 8; j++) v[j] = H1[(size_t)s[j] * HID + c];
        a0 = fmaf(v[0], n[0], a0);  a1 = fmaf(v[1], n[1], a1);
        a2 = fmaf(v[2], n[2], a2);  a3 = fmaf(v[3], n[3], a3);
        a0 = fmaf(v[4], n[4], a0);  a1 = fmaf(v[5], n[5], a1);
        a2 = fmaf(v[6], n[6], a2);  a3 = fmaf(v[7], n[7], a3);
    }
    for (int q = dl; q < d; ++q) {   // overflow fallback (never hit in practice)
        int2 t = es[beg + q];
        a0 = fmaf(H1[(size_t)t.x * HID + c], __int_as_float(t.y), a0);
    }

    float acc = (a0 + a1) + (a2 + a3);
    A1[(size_t)node * HID + c] = fmaxf(fmaf(di, acc, b1[c]), 0.0f);
}

// ---------------- GEMM2: H2[50000,40] = A1[50000,128] @ W2[128,40] ----------------

__global__ __launch_bounds__(256) void k_gemm2(const float* __restrict__ A1,
                                               const float* __restrict__ W2,
                                               float* __restrict__ H2) {
    __shared__ float Hs[64][129];
    __shared__ float Ws[128][40];
    const int tid = threadIdx.x;
    const int row0 = blockIdx.x * 64;

    for (int i = tid; i < HID * OUT_C; i += 256) Ws[i / OUT_C][i % OUT_C] = W2[i];
    for (int i = tid; i < 64 * HID; i += 256) {
        int r = i >> 7, k = i & 127;
        int grow = row0 + r;
        Hs[r][k] = (grow < N_NODES) ? A1[(size_t)grow * HID + k] : 0.0f;
    }
    __syncthreads();

    const int r  = tid >> 2;            // 0..63
    const int c0 = (tid & 3) * 10;      // 0,10,20,30
    float acc[10];
#pragma unroll
    for (int j = 0; j < 10; j++) acc[j] = 0.0f;

    for (int k = 0; k < HID; k++) {
        float h = Hs[r][k];
#pragma unroll
        for (int j = 0; j < 10; j++) acc[j] = fmaf(h, Ws[k][c0 + j], acc[j]);
    }

    int grow = row0 + r;
    if (grow < N_NODES) {
#pragma unroll
        for (int j = 0; j < 10; j++) H2[(size_t)grow * OUT_C + c0 + j] = acc[j];
    }
}

// ------- CSR aggregation layer 2 + bias fused with log_softmax -------

__global__ __launch_bounds__(256) void k_agg2_lsm(const int* __restrict__ rowptr,
                                                  const int2* __restrict__ es,
                                                  const float* __restrict__ dinv,
                                                  const float* __restrict__ H2,
                                                  const float* __restrict__ b2,
                                                  float* __restrict__ out) {
    __shared__ int2 sE[4][MAXDEG];
    const int tid  = threadIdx.x;
    const int wv   = tid >> 6;
    const int lane = tid & 63;
    const int node = blockIdx.x * 4 + wv;
    if (node >= N_NODES) return;

    const int beg = rowptr[node];
    const int d   = rowptr[node + 1] - beg;
    const int dl = (d < MAXDEG) ? d : MAXDEG;
    const int dp = (dl + 7) & ~7;
    for (int p = lane; p < dp; p += 64)
        sE[wv][p] = (p < dl) ? es[beg + p] : make_int2(0, 0);
    // wave-private LDS region: compiler-inserted lgkmcnt wait suffices

    float di = dinv[node];
    float a0 = 0.0f, a1 = 0.0f, a2 = 0.0f, a3 = 0.0f;
    if (lane < OUT_C) a0 = di * H2[(size_t)node * OUT_C + lane];

    for (int p = 0; p < dp; p += 8) {
        int s[8]; float n[8], v[8];
#pragma unroll
        for (int j = 0; j < 8; j++) {
            int2 t = sE[wv][p + j];
            s[j] = t.x; n[j] = __int_as_float(t.y);
        }
#pragma unroll
        for (int j = 0; j < 8; j++)
            v[j] = (lane < OUT_C) ? H2[(size_t)s[j] * OUT_C + lane] : 0.0f;
        a0 = fmaf(v[0], n[0], a0);  a1 = fmaf(v[1], n[1], a1);
        a2 = fmaf(v[2], n[2], a2);  a3 = fmaf(v[3], n[3], a3);
        a0 = fmaf(v[4], n[4], a0);  a1 = fmaf(v[5], n[5], a1);
        a2 = fmaf(v[6], n[6], a2);  a3 = fmaf(v[7], n[7], a3);
    }
    for (int q = dl; q < d; ++q)   // overflow fallback
        if (lane < OUT_C) {
            int2 t = es[beg + q];
            a0 = fmaf(H2[(size_t)t.x * OUT_C + lane], __int_as_float(t.y), a0);
        }

    float acc = (a0 + a1) + (a2 + a3);
    float v = (lane < OUT_C) ? fmaf(di, acc, b2[lane]) : -INFINITY;

    float m = v;
#pragma unroll
    for (int off = 32; off > 0; off >>= 1) m = fmaxf(m, __shfl_xor(m, off));
    float ex = (lane < OUT_C) ? __expf(v - m) : 0.0f;
    float s = ex;
#pragma unroll
    for (int off = 32; off > 0; off >>= 1) s += __shfl_xor(s, off);
    if (lane < OUT_C) out[(size_t)node * OUT_C + lane] = v - m - __logf(s);
}

// ---------------- launch ----------------

extern "C" void kernel_launch(void* const* d_in, const int* in_sizes, int n_in,
                              void* d_out, int out_size, void* d_ws, size_t ws_size,
                              hipStream_t stream) {
    const float* x  = (const float*)d_in[0];
    const int*   ei = (const int*)d_in[1];          // [2, E] int32
    const float* ew = (const float*)d_in[2];
    const float* W1 = (const float*)d_in[3];
    const float* b1 = (const float*)d_in[4];
    const float* W2 = (const float*)d_in[5];
    const float* b2 = (const float*)d_in[6];
    float* out = (float*)d_out;

    const int* row = ei;            // sources
    const int* col = ei + E_EDGES;  // targets

    // workspace layout (float units), ~58.5 MB total
    float* ws = (float*)d_ws;
    unsigned long long* packed = (unsigned long long*)ws;        // [0, 100000)
    float* dinv   = ws + 100000;                                 // [100000, 150000)
    int*   rowptr = (int*)(ws + 150000);                         // [150000, 200001)
    int*   bsum   = (int*)(ws + 200016);                         // [200016, 200272)
    int2*  es     = (int2*)(ws + 200272);                        // [200272, 1800272)
    float* H1     = ws + 1800272;                                // N*HID (16B aligned)
    float* A1     = H1 + (size_t)N_NODES * HID;
    unsigned short* W1bt = (unsigned short*)(A1 + (size_t)N_NODES * HID); // 128*512
    float* H2     = H1;                    // alias: H1 dead after agg1
    int*   rank   = (int*)H1;              // alias: rank dead before gemm1 writes H1

    const int B = 256;

    k_init<<<(N_NODES + B - 1) / B, B, 0, stream>>>(packed);
    k_deg_cnt_rank<<<(E_EDGES + B - 1) / B, B, 0, stream>>>(col, ew, packed, rank);
    k_dinv<<<(N_NODES + B - 1) / B, B, 0, stream>>>(packed, dinv);

    k_scan1<<<SCAN_BLOCKS, B, 0, stream>>>(packed, rowptr, bsum);
    k_scan2<<<1, B, 0, stream>>>(bsum);
    k_scan3<<<SCAN_BLOCKS, B, 0, stream>>>(rowptr, bsum);

    k_scatter<<<(E_EDGES + B - 1) / B, B, 0, stream>>>(row, col, ew, dinv,
                                                       rowptr, rank, es);

    k_w1t<<<(F_IN * HID) / B, B, 0, stream>>>(W1, W1bt);
    k_gemm1_mfma<<<(N_NODES + 127) / 128, B, 0, stream>>>(x, W1bt, H1);

    k_agg1_csr<<<(N_NODES + 1) / 2, B, 0, stream>>>(rowptr, es, dinv, H1, b1, A1);

    k_gemm2<<<(N_NODES + 63) / 64, B, 0, stream>>>(A1, W2, H2);

    k_agg2_lsm<<<(N_NODES + 3) / 4, B, 0, stream>>>(rowptr, es, dinv, H2, b2, out);
}

// Round 6
// 350.368 us; speedup vs baseline: 2.6571x; 1.0964x over previous
//
#include <hip/hip_runtime.h>
#include <math.h>

#define N_NODES 50000
#define F_IN    512
#define HID     128
#define OUT_C   40
#define E_EDGES 800000
#define SCAN_BLOCKS 196   // ceil(50000/256)
#define LDA 40            // padded k-stride (bf16 elems) for MFMA LDS tiles
#define MAXDEG 96         // LDS edge-stage capacity per node (max in-degree ~35)

typedef __attribute__((ext_vector_type(8))) short short8;
typedef __attribute__((ext_vector_type(4))) float f32x4;

__device__ __forceinline__ unsigned short f2bf(float f) {
    union { float f; unsigned u; } v; v.f = f;
    unsigned u = v.u + 0x7fffu + ((v.u >> 16) & 1u);   // RNE
    return (unsigned short)(u >> 16);
}

// -------- packed degree/count histogram: [63:40]=count, [39:0]=sum(w)*2^32 --------

__global__ void k_init(unsigned long long* __restrict__ packed) {
    int i = blockIdx.x * blockDim.x + threadIdx.x;
    if (i < N_NODES) packed[i] = 0ULL;
}

__global__ void k_deg_cnt_rank(const int* __restrict__ col, const float* __restrict__ w,
                               unsigned long long* __restrict__ packed,
                               int* __restrict__ rank) {
    int e = blockIdx.x * blockDim.x + threadIdx.x;
    if (e < E_EDGES) {
        int c = col[e];
        unsigned long long fx = (unsigned long long)(w[e] * 4294967296.0f);
        unsigned long long old = atomicAdd(&packed[c], (1ULL << 40) | fx);
        rank[e] = (int)(old >> 40);     // #earlier edges with same target = rank
    }
}

__global__ void k_dinv(const unsigned long long* __restrict__ packed,
                       float* __restrict__ dinv) {
    int i = blockIdx.x * blockDim.x + threadIdx.x;
    if (i < N_NODES) {
        float d = 1.0f + (float)(packed[i] & 0xFFFFFFFFFFULL) * (1.0f / 4294967296.0f);
        dinv[i] = rsqrtf(d);    // d >= 1 always (self-loop)
    }
}

// ---------------- exclusive scan of counts -> rowptr (3-stage) ----------------

__global__ __launch_bounds__(256) void k_scan1(const unsigned long long* __restrict__ packed,
                                               int* __restrict__ excl,
                                               int* __restrict__ bsum) {
    __shared__ int s[256];
    int tid = threadIdx.x;
    int i = blockIdx.x * 256 + tid;
    int v = (i < N_NODES) ? (int)(packed[i] >> 40) : 0;
    s[tid] = v;
    __syncthreads();
#pragma unroll
    for (int off = 1; off < 256; off <<= 1) {
        int t = (tid >= off) ? s[tid - off] : 0;
        __syncthreads();
        s[tid] += t;
        __syncthreads();
    }
    if (i < N_NODES) excl[i] = s[tid] - v;
    if (tid == 255) bsum[blockIdx.x] = s[255];
}

__global__ __launch_bounds__(256) void k_scan2(int* __restrict__ bsum) {
    __shared__ int s[256];
    int tid = threadIdx.x;
    int v = (tid < SCAN_BLOCKS) ? bsum[tid] : 0;
    s[tid] = v;
    __syncthreads();
#pragma unroll
    for (int off = 1; off < 256; off <<= 1) {
        int t = (tid >= off) ? s[tid - off] : 0;
        __syncthreads();
        s[tid] += t;
        __syncthreads();
    }
    if (tid < SCAN_BLOCKS) bsum[tid] = s[tid] - v;   // exclusive
}

__global__ __launch_bounds__(256) void k_scan3(int* __restrict__ rowptr,
                                               const int* __restrict__ bsum) {
    int i = blockIdx.x * 256 + threadIdx.x;
    if (i < N_NODES) rowptr[i] += bsum[blockIdx.x];
    if (i == 0) rowptr[N_NODES] = E_EDGES;
}

// ------- scatter edges into CSR order, atomic-free; fold pre=dinv[src]*w -------

__global__ void k_scatter(const int* __restrict__ row, const int* __restrict__ col,
                          const float* __restrict__ w, const float* __restrict__ dinv,
                          const int* __restrict__ rowptr, const int* __restrict__ rank,
                          int2* __restrict__ es) {
    int e = blockIdx.x * blockDim.x + threadIdx.x;
    if (e < E_EDGES) {
        int r = row[e], c = col[e];
        float pre = dinv[r] * w[e];
        int pos = rowptr[c] + rank[e];
        es[pos] = make_int2(r, __float_as_int(pre));
    }
}

// ---------------- W1^T -> bf16 prologue: W1bt[n][k] = bf16(W1[k][n]) ----------------

__global__ __launch_bounds__(256) void k_w1t(const float* __restrict__ W1,
                                             unsigned short* __restrict__ W1bt) {
    int idx = blockIdx.x * 256 + threadIdx.x;      // 65536 total
    int k = idx & 511, n = idx >> 9;
    W1bt[(size_t)n * F_IN + k] = f2bf(W1[(size_t)k * HID + n]);
}

// ------- GEMM1 (MFMA bf16): H1b[50000,128](bf16) = X[50000,512] @ W1[512,128] -------

__global__ __launch_bounds__(256) void k_gemm1_mfma(const float* __restrict__ X,
                                                    const unsigned short* __restrict__ W1bt,
                                                    unsigned short* __restrict__ Hb) {
    __shared__ __align__(16) unsigned short As[128 * LDA];
    __shared__ __align__(16) unsigned short Bs[128 * LDA];
    const int tid  = threadIdx.x;
    const int row0 = blockIdx.x * 128;
    const int lane = tid & 63;
    const int w    = tid >> 6;
    const int quad = lane >> 4;
    const int l16  = lane & 15;
    const int wm   = (w >> 1) * 64;
    const int wn   = (w & 1) * 64;

    f32x4 acc[4][4] = {};

    const int sr = tid >> 1;
    const int kg = (tid & 1) * 16;
    int arow = row0 + sr;
    if (arow >= N_NODES) arow = N_NODES - 1;          // clamp: rows are independent
    const float*          xp = X + (size_t)arow * F_IN + kg;
    const unsigned short* bp = W1bt + (size_t)sr * F_IN + kg;
    unsigned short* asw = &As[sr * LDA + kg];
    unsigned short* bsw = &Bs[sr * LDA + kg];

    for (int k0 = 0; k0 < F_IN; k0 += 32) {
        float4 xa = *(const float4*)(xp + k0);
        float4 xb = *(const float4*)(xp + k0 + 4);
        float4 xc = *(const float4*)(xp + k0 + 8);
        float4 xd = *(const float4*)(xp + k0 + 12);
        short8 pa, pb;
        pa[0] = (short)f2bf(xa.x); pa[1] = (short)f2bf(xa.y);
        pa[2] = (short)f2bf(xa.z); pa[3] = (short)f2bf(xa.w);
        pa[4] = (short)f2bf(xb.x); pa[5] = (short)f2bf(xb.y);
        pa[6] = (short)f2bf(xb.z); pa[7] = (short)f2bf(xb.w);
        pb[0] = (short)f2bf(xc.x); pb[1] = (short)f2bf(xc.y);
        pb[2] = (short)f2bf(xc.z); pb[3] = (short)f2bf(xc.w);
        pb[4] = (short)f2bf(xd.x); pb[5] = (short)f2bf(xd.y);
        pb[6] = (short)f2bf(xd.z); pb[7] = (short)f2bf(xd.w);
        short8 wa = *(const short8*)(bp + k0);
        short8 wb = *(const short8*)(bp + k0 + 8);

        *(short8*)(asw)     = pa;
        *(short8*)(asw + 8) = pb;
        *(short8*)(bsw)     = wa;
        *(short8*)(bsw + 8) = wb;
        __syncthreads();

        short8 af[4], bf[4];
#pragma unroll
        for (int i = 0; i < 4; i++)
            af[i] = *(const short8*)&As[(wm + i * 16 + l16) * LDA + quad * 8];
#pragma unroll
        for (int j = 0; j < 4; j++)
            bf[j] = *(const short8*)&Bs[(wn + j * 16 + l16) * LDA + quad * 8];
#pragma unroll
        for (int i = 0; i < 4; i++)
#pragma unroll
            for (int j = 0; j < 4; j++)
                acc[i][j] = __builtin_amdgcn_mfma_f32_16x16x32_bf16(
                    af[i], bf[j], acc[i][j], 0, 0, 0);
        __syncthreads();
    }

#pragma unroll
    for (int i = 0; i < 4; i++) {
#pragma unroll
        for (int r = 0; r < 4; r++) {
            int grow = row0 + wm + i * 16 + quad * 4 + r;
            if (grow < N_NODES) {
#pragma unroll
                for (int j = 0; j < 4; j++) {
                    int gcol = wn + j * 16 + l16;
                    Hb[(size_t)grow * HID + gcol] = f2bf(acc[i][j][r]);
                }
            }
        }
    }
}

// ------- CSR aggregation layer 1 on bf16 H1: one wave/node, 2 cols/thread -------
// relu(di*(sum pre*H1[s] + di*H1[node]) + b1), fp32 accumulation.

__global__ __launch_bounds__(256) void k_agg1_csr(const int* __restrict__ rowptr,
                                                  const int2* __restrict__ es,
                                                  const float* __restrict__ dinv,
                                                  const unsigned short* __restrict__ H1b,
                                                  const float* __restrict__ b1,
                                                  float* __restrict__ A1) {
    __shared__ int2 sE[4][MAXDEG];
    const int tid  = threadIdx.x;
    const int wv   = tid >> 6;
    const int lane = tid & 63;
    const int node = blockIdx.x * 4 + wv;          // 50000 % 4 == 0
    if (node >= N_NODES) return;

    const int beg = rowptr[node];
    const int d   = rowptr[node + 1] - beg;
    const int dl  = (d < MAXDEG) ? d : MAXDEG;
    const int dp  = (dl + 7) & ~7;
    for (int p = lane; p < dp; p += 64)
        sE[wv][p] = (p < dl) ? es[beg + p] : make_int2(0, 0);
    // wave-private LDS region: compiler-inserted lgkmcnt wait suffices

    const float di = dinv[node];
    const unsigned self = *(const unsigned*)&H1b[(size_t)node * HID + lane * 2];
    float al0 = di * __uint_as_float(self << 16);
    float ah0 = di * __uint_as_float(self & 0xffff0000u);
    float al1 = 0.0f, ah1 = 0.0f, al2 = 0.0f, ah2 = 0.0f, al3 = 0.0f, ah3 = 0.0f;

    for (int p = 0; p < dp; p += 8) {
        int s[8]; float n[8]; unsigned g[8];
#pragma unroll
        for (int j = 0; j < 8; j++) {
            int2 t = sE[wv][p + j];
            s[j] = t.x; n[j] = __int_as_float(t.y);
        }
#pragma unroll
        for (int j = 0; j < 8; j++)
            g[j] = *(const unsigned*)&H1b[(size_t)s[j] * HID + lane * 2];
        al0 = fmaf(__uint_as_float(g[0] << 16), n[0], al0);
        ah0 = fmaf(__uint_as_float(g[0] & 0xffff0000u), n[0], ah0);
        al1 = fmaf(__uint_as_float(g[1] << 16), n[1], al1);
        ah1 = fmaf(__uint_as_float(g[1] & 0xffff0000u), n[1], ah1);
        al2 = fmaf(__uint_as_float(g[2] << 16), n[2], al2);
        ah2 = fmaf(__uint_as_float(g[2] & 0xffff0000u), n[2], ah2);
        al3 = fmaf(__uint_as_float(g[3] << 16), n[3], al3);
        ah3 = fmaf(__uint_as_float(g[3] & 0xffff0000u), n[3], ah3);
        al0 = fmaf(__uint_as_float(g[4] << 16), n[4], al0);
        ah0 = fmaf(__uint_as_float(g[4] & 0xffff0000u), n[4], ah0);
        al1 = fmaf(__uint_as_float(g[5] << 16), n[5], al1);
        ah1 = fmaf(__uint_as_float(g[5] & 0xffff0000u), n[5], ah1);
        al2 = fmaf(__uint_as_float(g[6] << 16), n[6], al2);
        ah2 = fmaf(__uint_as_float(g[6] & 0xffff0000u), n[6], ah2);
        al3 = fmaf(__uint_as_float(g[7] << 16), n[7], al3);
        ah3 = fmaf(__uint_as_float(g[7] & 0xffff0000u), n[7], ah3);
    }
    for (int q = dl; q < d; ++q) {   // overflow fallback (never hit in practice)
        int2 t = es[beg + q];
        unsigned g = *(const unsigned*)&H1b[(size_t)t.x * HID + lane * 2];
        float nm = __int_as_float(t.y);
        al0 = fmaf(__uint_as_float(g << 16), nm, al0);
        ah0 = fmaf(__uint_as_float(g & 0xffff0000u), nm, ah0);
    }

    const float accl = (al0 + al1) + (al2 + al3);
    const float acch = (ah0 + ah1) + (ah2 + ah3);
    const int c = lane * 2;
    float2 r;
    r.x = fmaxf(fmaf(di, accl, b1[c]), 0.0f);
    r.y = fmaxf(fmaf(di, acch, b1[c + 1]), 0.0f);
    *(float2*)&A1[(size_t)node * HID + c] = r;
}

// ---------------- GEMM2: H2[50000,40] = A1[50000,128] @ W2[128,40] ----------------

__global__ __launch_bounds__(256) void k_gemm2(const float* __restrict__ A1,
                                               const float* __restrict__ W2,
                                               float* __restrict__ H2) {
    __shared__ float Hs[64][129];
    __shared__ float Ws[128][40];
    const int tid = threadIdx.x;
    const int row0 = blockIdx.x * 64;

    for (int i = tid; i < HID * OUT_C; i += 256) Ws[i / OUT_C][i % OUT_C] = W2[i];
    for (int i = tid; i < 64 * HID; i += 256) {
        int r = i >> 7, k = i & 127;
        int grow = row0 + r;
        Hs[r][k] = (grow < N_NODES) ? A1[(size_t)grow * HID + k] : 0.0f;
    }
    __syncthreads();

    const int r  = tid >> 2;            // 0..63
    const int c0 = (tid & 3) * 10;      // 0,10,20,30
    float acc[10];
#pragma unroll
    for (int j = 0; j < 10; j++) acc[j] = 0.0f;

    for (int k = 0; k < HID; k++) {
        float h = Hs[r][k];
#pragma unroll
        for (int j = 0; j < 10; j++) acc[j] = fmaf(h, Ws[k][c0 + j], acc[j]);
    }

    int grow = row0 + r;
    if (grow < N_NODES) {
#pragma unroll
        for (int j = 0; j < 10; j++) H2[(size_t)grow * OUT_C + c0 + j] = acc[j];
    }
}

// ------- CSR aggregation layer 2 + bias fused with log_softmax -------

__global__ __launch_bounds__(256) void k_agg2_lsm(const int* __restrict__ rowptr,
                                                  const int2* __restrict__ es,
                                                  const float* __restrict__ dinv,
                                                  const float* __restrict__ H2,
                                                  const float* __restrict__ b2,
                                                  float* __restrict__ out) {
    __shared__ int2 sE[4][MAXDEG];
    const int tid  = threadIdx.x;
    const int wv   = tid >> 6;
    const int lane = tid & 63;
    const int node = blockIdx.x * 4 + wv;
    if (node >= N_NODES) return;

    const int beg = rowptr[node];
    const int d   = rowptr[node + 1] - beg;
    const int dl = (d < MAXDEG) ? d : MAXDEG;
    const int dp = (dl + 7) & ~7;
    for (int p = lane; p < dp; p += 64)
        sE[wv][p] = (p < dl) ? es[beg + p] : make_int2(0, 0);
    // wave-private LDS region: compiler-inserted lgkmcnt wait suffices

    float di = dinv[node];
    float a0 = 0.0f, a1 = 0.0f, a2 = 0.0f, a3 = 0.0f;
    if (lane < OUT_C) a0 = di * H2[(size_t)node * OUT_C + lane];

    for (int p = 0; p < dp; p += 8) {
        int s[8]; float n[8], v[8];
#pragma unroll
        for (int j = 0; j < 8; j++) {
            int2 t = sE[wv][p + j];
            s[j] = t.x; n[j] = __int_as_float(t.y);
        }
#pragma unroll
        for (int j = 0; j < 8; j++)
            v[j] = (lane < OUT_C) ? H2[(size_t)s[j] * OUT_C + lane] : 0.0f;
        a0 = fmaf(v[0], n[0], a0);  a1 = fmaf(v[1], n[1], a1);
        a2 = fmaf(v[2], n[2], a2);  a3 = fmaf(v[3], n[3], a3);
        a0 = fmaf(v[4], n[4], a0);  a1 = fmaf(v[5], n[5], a1);
        a2 = fmaf(v[6], n[6], a2);  a3 = fmaf(v[7], n[7], a3);
    }
    for (int q = dl; q < d; ++q)   // overflow fallback
        if (lane < OUT_C) {
            int2 t = es[beg + q];
            a0 = fmaf(H2[(size_t)t.x * OUT_C + lane], __int_as_float(t.y), a0);
        }

    float acc = (a0 + a1) + (a2 + a3);
    float v = (lane < OUT_C) ? fmaf(di, acc, b2[lane]) : -INFINITY;

    float m = v;
#pragma unroll
    for (int off = 32; off > 0; off >>= 1) m = fmaxf(m, __shfl_xor(m, off));
    float ex = (lane < OUT_C) ? __expf(v - m) : 0.0f;
    float s = ex;
#pragma unroll
    for (int off = 32; off > 0; off >>= 1) s += __shfl_xor(s, off);
    if (lane < OUT_C) out[(size_t)node * OUT_C + lane] = v - m - __logf(s);
}

// ---------------- launch ----------------

extern "C" void kernel_launch(void* const* d_in, const int* in_sizes, int n_in,
                              void* d_out, int out_size, void* d_ws, size_t ws_size,
                              hipStream_t stream) {
    const float* x  = (const float*)d_in[0];
    const int*   ei = (const int*)d_in[1];          // [2, E] int32
    const float* ew = (const float*)d_in[2];
    const float* W1 = (const float*)d_in[3];
    const float* b1 = (const float*)d_in[4];
    const float* W2 = (const float*)d_in[5];
    const float* b2 = (const float*)d_in[6];
    float* out = (float*)d_out;

    const int* row = ei;            // sources
    const int* col = ei + E_EDGES;  // targets

    // workspace layout (float units), ~45.8 MB total
    float* ws = (float*)d_ws;
    unsigned long long* packed = (unsigned long long*)ws;        // [0, 100000)
    float* dinv   = ws + 100000;                                 // [100000, 150000)
    int*   rowptr = (int*)(ws + 150000);                         // [150000, 200001)
    int*   bsum   = (int*)(ws + 200016);                         // [200016, 200272)
    int2*  es     = (int2*)(ws + 200272);                        // [200272, 1800272)
    unsigned short* H1b = (unsigned short*)(ws + 1800272);       // N*HID bf16 (3.2M floats)
    float* A1     = ws + 1800272 + 3200000;                      // N*HID fp32
    unsigned short* W1bt = (unsigned short*)(A1 + (size_t)N_NODES * HID); // 128*512
    float* H2     = (float*)H1b;           // alias: H1b dead after agg1 (8MB < 12.8MB)
    int*   rank   = (int*)H1b;             // alias: rank dead before gemm1 writes H1b

    const int B = 256;

    k_init<<<(N_NODES + B - 1) / B, B, 0, stream>>>(packed);
    k_deg_cnt_rank<<<(E_EDGES + B - 1) / B, B, 0, stream>>>(col, ew, packed, rank);
    k_dinv<<<(N_NODES + B - 1) / B, B, 0, stream>>>(packed, dinv);

    k_scan1<<<SCAN_BLOCKS, B, 0, stream>>>(packed, rowptr, bsum);
    k_scan2<<<1, B, 0, stream>>>(bsum);
    k_scan3<<<SCAN_BLOCKS, B, 0, stream>>>(rowptr, bsum);

    k_scatter<<<(E_EDGES + B - 1) / B, B, 0, stream>>>(row, col, ew, dinv,
                                                       rowptr, rank, es);

    k_w1t<<<(F_IN * HID) / B, B, 0, stream>>>(W1, W1bt);
    k_gemm1_mfma<<<(N_NODES + 127) / 128, B, 0, stream>>>(x, W1bt, H1b);

    k_agg1_csr<<<(N_NODES + 3) / 4, B, 0, stream>>>(rowptr, es, dinv, H1b, b1, A1);

    k_gemm2<<<(N_NODES + 63) / 64, B, 0, stream>>>(A1, W2, H2);

    k_agg2_lsm<<<(N_NODES + 3) / 4, B, 0, stream>>>(rowptr, es, dinv, H2, b2, out);
}

// Round 7
// 310.037 us; speedup vs baseline: 3.0027x; 1.1301x over previous
//
#include <hip/hip_runtime.h>
#include <math.h>

#define N_NODES 50000
#define F_IN    512
#define HID     128
#define OUT_C   40
#define NPAD    48        // padded output cols for gemm2 MFMA
#define E_EDGES 800000
#define SCAN_BLOCKS 196   // ceil(50000/256)
#define LDA 40            // padded k-stride (bf16) for gemm1 LDS tiles
#define LDK 136           // padded k-stride (bf16) for gemm2 LDS tiles
#define MAXDEG 96         // LDS edge-stage capacity (max in-degree ~35)
#define G1B 391           // gemm1 blocks = ceil(50000/128)
#define DEGB 3125         // deg blocks = 800000/256

typedef __attribute__((ext_vector_type(8))) short short8;
typedef __attribute__((ext_vector_type(4))) float f32x4;

__device__ __forceinline__ unsigned short f2bf(float f) {
    union { float f; unsigned u; } v; v.f = f;
    unsigned u = v.u + 0x7fffu + ((v.u >> 16) & 1u);   // RNE
    return (unsigned short)(u >> 16);
}
__device__ __forceinline__ float bf2f(unsigned short h) {
    return __uint_as_float((unsigned)h << 16);
}

// ---------------- init packed histogram ----------------

__global__ void k_init(unsigned long long* __restrict__ packed) {
    int i = blockIdx.x * blockDim.x + threadIdx.x;
    if (i < N_NODES) packed[i] = 0ULL;
}

// -------- weight prep: W1bt[n][k]=bf16(W1[k][n]); W2bt[n][k]=bf16(W2[k][n]) --------

__global__ __launch_bounds__(256) void k_wprep(const float* __restrict__ W1,
                                               const float* __restrict__ W2,
                                               unsigned short* __restrict__ W1bt,
                                               unsigned short* __restrict__ W2bt) {
    int idx = blockIdx.x * 256 + threadIdx.x;
    if (idx < F_IN * HID) {
        int k = idx & 511, n = idx >> 9;
        W1bt[(size_t)n * F_IN + k] = f2bf(W1[(size_t)k * HID + n]);
    } else if (idx < F_IN * HID + NPAD * HID) {
        int i2 = idx - F_IN * HID;
        int k = i2 & 127, n = i2 >> 7;
        W2bt[n * HID + k] = (n < OUT_C) ? f2bf(W2[(size_t)k * OUT_C + n]) : 0;
    }
}

// ------- FUSED: gemm1 (MFMA bf16, blocks [0,G1B)) + deg/cnt/rank (rest) -------
// The two jobs are independent; deg blocks are atomic-latency-bound (VALU ~0%)
// and backfill wave slots behind the LDS/MFMA-bound gemm blocks.

__global__ __launch_bounds__(256) void k_g1deg(const float* __restrict__ X,
                                               const unsigned short* __restrict__ W1bt,
                                               unsigned short* __restrict__ Hb,
                                               const int* __restrict__ col,
                                               const float* __restrict__ ew,
                                               unsigned long long* __restrict__ packed,
                                               int* __restrict__ rank) {
    const int tid = threadIdx.x;
    if (blockIdx.x >= G1B) {
        int e = (blockIdx.x - G1B) * 256 + tid;
        if (e < E_EDGES) {
            int c = col[e];
            unsigned long long fx = (unsigned long long)(ew[e] * 4294967296.0f);
            unsigned long long old = atomicAdd(&packed[c], (1ULL << 40) | fx);
            rank[e] = (int)(old >> 40);
        }
        return;
    }

    __shared__ __align__(16) unsigned short As[128 * LDA];
    __shared__ __align__(16) unsigned short Bs[128 * LDA];
    const int row0 = blockIdx.x * 128;
    const int lane = tid & 63;
    const int w    = tid >> 6;
    const int quad = lane >> 4;
    const int l16  = lane & 15;
    const int wm   = (w >> 1) * 64;
    const int wn   = (w & 1) * 64;

    f32x4 acc[4][4] = {};

    const int sr = tid >> 1;
    const int kg = (tid & 1) * 16;
    int arow = row0 + sr;
    if (arow >= N_NODES) arow = N_NODES - 1;          // clamp: rows independent
    const float*          xp = X + (size_t)arow * F_IN + kg;
    const unsigned short* bp = W1bt + (size_t)sr * F_IN + kg;
    unsigned short* asw = &As[sr * LDA + kg];
    unsigned short* bsw = &Bs[sr * LDA + kg];

    for (int k0 = 0; k0 < F_IN; k0 += 32) {
        float4 xa = *(const float4*)(xp + k0);
        float4 xb = *(const float4*)(xp + k0 + 4);
        float4 xc = *(const float4*)(xp + k0 + 8);
        float4 xd = *(const float4*)(xp + k0 + 12);
        short8 pa, pb;
        pa[0] = (short)f2bf(xa.x); pa[1] = (short)f2bf(xa.y);
        pa[2] = (short)f2bf(xa.z); pa[3] = (short)f2bf(xa.w);
        pa[4] = (short)f2bf(xb.x); pa[5] = (short)f2bf(xb.y);
        pa[6] = (short)f2bf(xb.z); pa[7] = (short)f2bf(xb.w);
        pb[0] = (short)f2bf(xc.x); pb[1] = (short)f2bf(xc.y);
        pb[2] = (short)f2bf(xc.z); pb[3] = (short)f2bf(xc.w);
        pb[4] = (short)f2bf(xd.x); pb[5] = (short)f2bf(xd.y);
        pb[6] = (short)f2bf(xd.z); pb[7] = (short)f2bf(xd.w);
        short8 wa = *(const short8*)(bp + k0);
        short8 wb = *(const short8*)(bp + k0 + 8);

        *(short8*)(asw)     = pa;
        *(short8*)(asw + 8) = pb;
        *(short8*)(bsw)     = wa;
        *(short8*)(bsw + 8) = wb;
        __syncthreads();

        short8 af[4], bf[4];
#pragma unroll
        for (int i = 0; i < 4; i++)
            af[i] = *(const short8*)&As[(wm + i * 16 + l16) * LDA + quad * 8];
#pragma unroll
        for (int j = 0; j < 4; j++)
            bf[j] = *(const short8*)&Bs[(wn + j * 16 + l16) * LDA + quad * 8];
#pragma unroll
        for (int i = 0; i < 4; i++)
#pragma unroll
            for (int j = 0; j < 4; j++)
                acc[i][j] = __builtin_amdgcn_mfma_f32_16x16x32_bf16(
                    af[i], bf[j], acc[i][j], 0, 0, 0);
        __syncthreads();
    }

#pragma unroll
    for (int i = 0; i < 4; i++) {
#pragma unroll
        for (int r = 0; r < 4; r++) {
            int grow = row0 + wm + i * 16 + quad * 4 + r;
            if (grow < N_NODES) {
#pragma unroll
                for (int j = 0; j < 4; j++) {
                    int gcol = wn + j * 16 + l16;
                    Hb[(size_t)grow * HID + gcol] = f2bf(acc[i][j][r]);
                }
            }
        }
    }
}

// ---------------- scan stage 1 (+ fused dinv) ----------------

__global__ __launch_bounds__(256) void k_scan1(const unsigned long long* __restrict__ packed,
                                               int* __restrict__ excl,
                                               int* __restrict__ bsum,
                                               float* __restrict__ dinv) {
    __shared__ int s[256];
    int tid = threadIdx.x;
    int i = blockIdx.x * 256 + tid;
    unsigned long long pk = (i < N_NODES) ? packed[i] : 0ULL;
    int v = (int)(pk >> 40);
    if (i < N_NODES) {
        float d = 1.0f + (float)(pk & 0xFFFFFFFFFFULL) * (1.0f / 4294967296.0f);
        dinv[i] = rsqrtf(d);    // d >= 1 (self-loop)
    }
    s[tid] = v;
    __syncthreads();
#pragma unroll
    for (int off = 1; off < 256; off <<= 1) {
        int t = (tid >= off) ? s[tid - off] : 0;
        __syncthreads();
        s[tid] += t;
        __syncthreads();
    }
    if (i < N_NODES) excl[i] = s[tid] - v;
    if (tid == 255) bsum[blockIdx.x] = s[255];
}

__global__ __launch_bounds__(256) void k_scan2(int* __restrict__ bsum) {
    __shared__ int s[256];
    int tid = threadIdx.x;
    int v = (tid < SCAN_BLOCKS) ? bsum[tid] : 0;
    s[tid] = v;
    __syncthreads();
#pragma unroll
    for (int off = 1; off < 256; off <<= 1) {
        int t = (tid >= off) ? s[tid - off] : 0;
        __syncthreads();
        s[tid] += t;
        __syncthreads();
    }
    if (tid < SCAN_BLOCKS) bsum[tid] = s[tid] - v;   // exclusive
}

__global__ __launch_bounds__(256) void k_scan3(int* __restrict__ rowptr,
                                               const int* __restrict__ bsum) {
    int i = blockIdx.x * 256 + threadIdx.x;
    if (i < N_NODES) rowptr[i] += bsum[blockIdx.x];
    if (i == 0) rowptr[N_NODES] = E_EDGES;
}

// ------- scatter edges into CSR order, atomic-free; fold pre=dinv[src]*w -------

__global__ void k_scatter(const int* __restrict__ row, const int* __restrict__ col,
                          const float* __restrict__ w, const float* __restrict__ dinv,
                          const int* __restrict__ rowptr, const int* __restrict__ rank,
                          int2* __restrict__ es) {
    int e = blockIdx.x * blockDim.x + threadIdx.x;
    if (e < E_EDGES) {
        int r = row[e], c = col[e];
        float pre = dinv[r] * w[e];
        int pos = rowptr[c] + rank[e];
        es[pos] = make_int2(r, __float_as_int(pre));
    }
}

// ------- CSR agg layer 1 on bf16 H1, bf16 A1 out: one wave/node, 2 cols/thread -------

__global__ __launch_bounds__(256) void k_agg1_csr(const int* __restrict__ rowptr,
                                                  const int2* __restrict__ es,
                                                  const float* __restrict__ dinv,
                                                  const unsigned short* __restrict__ H1b,
                                                  const float* __restrict__ b1,
                                                  unsigned short* __restrict__ A1b) {
    __shared__ int2 sE[4][MAXDEG];
    const int tid  = threadIdx.x;
    const int wv   = tid >> 6;
    const int lane = tid & 63;
    const int node = blockIdx.x * 4 + wv;          // 50000 % 4 == 0
    if (node >= N_NODES) return;

    const int beg = rowptr[node];
    const int d   = rowptr[node + 1] - beg;
    const int dl  = (d < MAXDEG) ? d : MAXDEG;
    const int dp  = (dl + 7) & ~7;
    for (int p = lane; p < dp; p += 64)
        sE[wv][p] = (p < dl) ? es[beg + p] : make_int2(0, 0);
    // wave-private LDS region: compiler-inserted lgkmcnt wait suffices

    const float di = dinv[node];
    const unsigned self = *(const unsigned*)&H1b[(size_t)node * HID + lane * 2];
    float al0 = di * __uint_as_float(self << 16);
    float ah0 = di * __uint_as_float(self & 0xffff0000u);
    float al1 = 0.0f, ah1 = 0.0f, al2 = 0.0f, ah2 = 0.0f, al3 = 0.0f, ah3 = 0.0f;

    for (int p = 0; p < dp; p += 8) {
        int s[8]; float n[8]; unsigned g[8];
#pragma unroll
        for (int j = 0; j < 8; j++) {
            int2 t = sE[wv][p + j];
            s[j] = t.x; n[j] = __int_as_float(t.y);
        }
#pragma unroll
        for (int j = 0; j < 8; j++)
            g[j] = *(const unsigned*)&H1b[(size_t)s[j] * HID + lane * 2];
        al0 = fmaf(__uint_as_float(g[0] << 16), n[0], al0);
        ah0 = fmaf(__uint_as_float(g[0] & 0xffff0000u), n[0], ah0);
        al1 = fmaf(__uint_as_float(g[1] << 16), n[1], al1);
        ah1 = fmaf(__uint_as_float(g[1] & 0xffff0000u), n[1], ah1);
        al2 = fmaf(__uint_as_float(g[2] << 16), n[2], al2);
        ah2 = fmaf(__uint_as_float(g[2] & 0xffff0000u), n[2], ah2);
        al3 = fmaf(__uint_as_float(g[3] << 16), n[3], al3);
        ah3 = fmaf(__uint_as_float(g[3] & 0xffff0000u), n[3], ah3);
        al0 = fmaf(__uint_as_float(g[4] << 16), n[4], al0);
        ah0 = fmaf(__uint_as_float(g[4] & 0xffff0000u), n[4], ah0);
        al1 = fmaf(__uint_as_float(g[5] << 16), n[5], al1);
        ah1 = fmaf(__uint_as_float(g[5] & 0xffff0000u), n[5], ah1);
        al2 = fmaf(__uint_as_float(g[6] << 16), n[6], al2);
        ah2 = fmaf(__uint_as_float(g[6] & 0xffff0000u), n[6], ah2);
        al3 = fmaf(__uint_as_float(g[7] << 16), n[7], al3);
        ah3 = fmaf(__uint_as_float(g[7] & 0xffff0000u), n[7], ah3);
    }
    for (int q = dl; q < d; ++q) {   // overflow fallback (never hit in practice)
        int2 t = es[beg + q];
        unsigned g = *(const unsigned*)&H1b[(size_t)t.x * HID + lane * 2];
        float nm = __int_as_float(t.y);
        al0 = fmaf(__uint_as_float(g << 16), nm, al0);
        ah0 = fmaf(__uint_as_float(g & 0xffff0000u), nm, ah0);
    }

    const float accl = (al0 + al1) + (al2 + al3);
    const float acch = (ah0 + ah1) + (ah2 + ah3);
    const int c = lane * 2;
    float rx = fmaxf(fmaf(di, accl, b1[c]), 0.0f);
    float ry = fmaxf(fmaf(di, acch, b1[c + 1]), 0.0f);
    unsigned pack = (unsigned)f2bf(rx) | ((unsigned)f2bf(ry) << 16);
    *(unsigned*)&A1b[(size_t)node * HID + c] = pack;
}

// ------- GEMM2 (MFMA bf16): H2b[50000,48] = A1b[50000,128] @ W2bt^T -------

__global__ __launch_bounds__(256) void k_gemm2_mfma(const unsigned short* __restrict__ A1b,
                                                    const unsigned short* __restrict__ W2bt,
                                                    unsigned short* __restrict__ H2b) {
    __shared__ __align__(16) unsigned short As[128 * LDK];
    __shared__ __align__(16) unsigned short Bs[NPAD * LDK];
    const int tid  = threadIdx.x;
    const int row0 = blockIdx.x * 128;
    const int lane = tid & 63;
    const int w    = tid >> 6;
    const int quad = lane >> 4;
    const int l16  = lane & 15;

    // stage A: 128 rows x 128 k (ushort8 chunks)
#pragma unroll
    for (int i = 0; i < 8; i++) {
        int id = tid + i * 256;
        int r = id >> 4, kc = (id & 15) * 8;
        int ar = row0 + r; if (ar >= N_NODES) ar = N_NODES - 1;
        *(short8*)&As[r * LDK + kc] = *(const short8*)&A1b[(size_t)ar * HID + kc];
    }
    // stage B: 48 rows x 128 k
#pragma unroll
    for (int i = 0; i < 3; i++) {
        int id = tid + i * 256;
        int n = id >> 4, kc = (id & 15) * 8;
        *(short8*)&Bs[n * LDK + kc] = *(const short8*)&W2bt[n * HID + kc];
    }
    __syncthreads();

    f32x4 acc[2][3] = {};
    const int rbase = w * 32;
#pragma unroll
    for (int ks = 0; ks < 4; ks++) {
        const int k0 = ks * 32 + quad * 8;
        short8 af[2], bf[3];
#pragma unroll
        for (int i = 0; i < 2; i++)
            af[i] = *(const short8*)&As[(rbase + i * 16 + l16) * LDK + k0];
#pragma unroll
        for (int j = 0; j < 3; j++)
            bf[j] = *(const short8*)&Bs[(j * 16 + l16) * LDK + k0];
#pragma unroll
        for (int i = 0; i < 2; i++)
#pragma unroll
            for (int j = 0; j < 3; j++)
                acc[i][j] = __builtin_amdgcn_mfma_f32_16x16x32_bf16(
                    af[i], bf[j], acc[i][j], 0, 0, 0);
    }

#pragma unroll
    for (int i = 0; i < 2; i++) {
#pragma unroll
        for (int r = 0; r < 4; r++) {
            int grow = row0 + rbase + i * 16 + quad * 4 + r;
            if (grow < N_NODES) {
#pragma unroll
                for (int j = 0; j < 3; j++)
                    H2b[(size_t)grow * NPAD + j * 16 + l16] = f2bf(acc[i][j][r]);
            }
        }
    }
}

// ------- CSR agg layer 2 (bf16 H2b) + bias fused with log_softmax -------

__global__ __launch_bounds__(256) void k_agg2_lsm(const int* __restrict__ rowptr,
                                                  const int2* __restrict__ es,
                                                  const float* __restrict__ dinv,
                                                  const unsigned short* __restrict__ H2b,
                                                  const float* __restrict__ b2,
                                                  float* __restrict__ out) {
    __shared__ int2 sE[4][MAXDEG];
    const int tid  = threadIdx.x;
    const int wv   = tid >> 6;
    const int lane = tid & 63;
    const int node = blockIdx.x * 4 + wv;
    if (node >= N_NODES) return;

    const int beg = rowptr[node];
    const int d   = rowptr[node + 1] - beg;
    const int dl = (d < MAXDEG) ? d : MAXDEG;
    const int dp = (dl + 7) & ~7;
    for (int p = lane; p < dp; p += 64)
        sE[wv][p] = (p < dl) ? es[beg + p] : make_int2(0, 0);
    // wave-private LDS region

    float di = dinv[node];
    float a0 = 0.0f, a1 = 0.0f, a2 = 0.0f, a3 = 0.0f;
    if (lane < OUT_C) a0 = di * bf2f(H2b[(size_t)node * NPAD + lane]);

    for (int p = 0; p < dp; p += 8) {
        int s[8]; float n[8], v[8];
#pragma unroll
        for (int j = 0; j < 8; j++) {
            int2 t = sE[wv][p + j];
            s[j] = t.x; n[j] = __int_as_float(t.y);
        }
#pragma unroll
        for (int j = 0; j < 8; j++)
            v[j] = (lane < OUT_C) ? bf2f(H2b[(size_t)s[j] * NPAD + lane]) : 0.0f;
        a0 = fmaf(v[0], n[0], a0);  a1 = fmaf(v[1], n[1], a1);
        a2 = fmaf(v[2], n[2], a2);  a3 = fmaf(v[3], n[3], a3);
        a0 = fmaf(v[4], n[4], a0);  a1 = fmaf(v[5], n[5], a1);
        a2 = fmaf(v[6], n[6], a2);  a3 = fmaf(v[7], n[7], a3);
    }
    for (int q = dl; q < d; ++q)   // overflow fallback
        if (lane < OUT_C) {
            int2 t = es[beg + q];
            a0 = fmaf(bf2f(H2b[(size_t)t.x * NPAD + lane]), __int_as_float(t.y), a0);
        }

    float acc = (a0 + a1) + (a2 + a3);
    float v = (lane < OUT_C) ? fmaf(di, acc, b2[lane]) : -INFINITY;

    float m = v;
#pragma unroll
    for (int off = 32; off > 0; off >>= 1) m = fmaxf(m, __shfl_xor(m, off));
    float ex = (lane < OUT_C) ? __expf(v - m) : 0.0f;
    float s = ex;
#pragma unroll
    for (int off = 32; off > 0; off >>= 1) s += __shfl_xor(s, off);
    if (lane < OUT_C) out[(size_t)node * OUT_C + lane] = v - m - __logf(s);
}

// ---------------- launch ----------------

extern "C" void kernel_launch(void* const* d_in, const int* in_sizes, int n_in,
                              void* d_out, int out_size, void* d_ws, size_t ws_size,
                              hipStream_t stream) {
    const float* x  = (const float*)d_in[0];
    const int*   ei = (const int*)d_in[1];          // [2, E] int32
    const float* ew = (const float*)d_in[2];
    const float* W1 = (const float*)d_in[3];
    const float* b1 = (const float*)d_in[4];
    const float* W2 = (const float*)d_in[5];
    const float* b2 = (const float*)d_in[6];
    float* out = (float*)d_out;

    const int* row = ei;            // sources
    const int* col = ei + E_EDGES;  // targets

    // workspace layout (float units), ~41 MB, no aliasing
    float* ws = (float*)d_ws;
    unsigned long long* packed = (unsigned long long*)ws;          // [0, 100000)
    float* dinv   = ws + 100000;                                   // 50000
    int*   rowptr = (int*)(ws + 150000);                           // 50001
    int*   bsum   = (int*)(ws + 200016);                           // 256
    int2*  es     = (int2*)(ws + 200272);                          // E int2
    int*   rank   = (int*)(ws + 1800272);                          // E
    unsigned short* H1b  = (unsigned short*)(ws + 2600272);        // N*HID bf16
    unsigned short* A1b  = (unsigned short*)(ws + 5800272);        // N*HID bf16
    unsigned short* W1bt = (unsigned short*)(ws + 9000272);        // 128*512 bf16
    unsigned short* W2bt = (unsigned short*)(ws + 9033040);        // 48*128 bf16
    unsigned short* H2b  = (unsigned short*)(ws + 9036112);        // N*48 bf16

    const int B = 256;

    k_init<<<(N_NODES + B - 1) / B, B, 0, stream>>>(packed);
    k_wprep<<<(F_IN * HID + NPAD * HID + B - 1) / B, B, 0, stream>>>(W1, W2, W1bt, W2bt);

    k_g1deg<<<G1B + DEGB, B, 0, stream>>>(x, W1bt, H1b, col, ew, packed, rank);

    k_scan1<<<SCAN_BLOCKS, B, 0, stream>>>(packed, rowptr, bsum, dinv);
    k_scan2<<<1, B, 0, stream>>>(bsum);
    k_scan3<<<SCAN_BLOCKS, B, 0, stream>>>(rowptr, bsum);

    k_scatter<<<(E_EDGES + B - 1) / B, B, 0, stream>>>(row, col, ew, dinv,
                                                       rowptr, rank, es);

    k_agg1_csr<<<(N_NODES + 3) / 4, B, 0, stream>>>(rowptr, es, dinv, H1b, b1, A1b);

    k_gemm2_mfma<<<(N_NODES + 127) / 128, B, 0, stream>>>(A1b, W2bt, H2b);

    k_agg2_lsm<<<(N_NODES + 3) / 4, B, 0, stream>>>(rowptr, es, dinv, H2b, b2, out);
}